// Round 3
// baseline (671.431 us; speedup 1.0000x reference)
//
#include <hip/hip_runtime.h>

// ---------------------------------------------------------------------------
// MultiScaleFeatureFusion — restructured:
//   scale0: x1 [4,512,16,16]  d=64 C=512 hs=16 Ns=256
//   scale1: x2 [4,256,32,32]  d=32 C=256 hs=32 Ns=1024
//   scale2: x3 [4,128,64,64]  d=16 C=128 hs=64 Ns=4096
// R3: logits factorization for upsampled scales — native logit GEMM (phase A)
// + bilerp-softmax-accumulate (phase B). Scale2 flash attention with NB=4.
// ---------------------------------------------------------------------------

#define BB 4
static constexpr int NC = 16;   // partial chunks per scale (uniform)

static constexpr int OFF_WP0 = 0;                       // 161*512
static constexpr int OFF_WP1 = OFF_WP0 + 161 * 512;
static constexpr int OFF_WP2 = OFF_WP1 + 97 * 256;
static constexpr int OFF_B0  = OFF_WP2 + 65 * 128;
static constexpr int OFF_B1  = OFF_B0 + 192;
static constexpr int OFF_B2  = OFF_B1 + 128;
static constexpr int OFF_PROJ0 = OFF_B2 + 96;
static constexpr int OFF_PROJ1 = OFF_PROJ0 + BB * 161 * 256;
static constexpr int OFF_PROJ2 = OFF_PROJ1 + BB * 97 * 1024;
static constexpr int OFF_BIGQ0 = OFF_PROJ2 + BB * 65 * 4096;   // [b][64][4096]
static constexpr int OFF_SBIG0 = OFF_BIGQ0 + BB * 64 * 4096;   // [b][4096]
static constexpr int OFF_BIGQ1 = OFF_SBIG0 + BB * 4096;        // [b][32][4096]
static constexpr int OFF_SBIG1 = OFF_BIGQ1 + BB * 32 * 4096;   // [b][4096]
static constexpr int OFF_LNAT  = OFF_SBIG1 + BB * 4096;        // shared: max(4*256*4096, 4*1024*1024)
static constexpr int OFF_MPART = OFF_LNAT + BB * 1024 * 1024;  // shared: 131072
static constexpr int PS = BB * NC * 4096;
static constexpr int OFF_PM  = OFF_MPART + 131072;
static constexpr int OFF_PSN = OFF_PM + 3 * PS;
static constexpr int OFF_PSW = OFF_PSN + 3 * PS;
static constexpr int OFF_A   = OFF_PSW + 3 * PS;               // 3*B*4096

// --------------------------- pack kernel -----------------------------------
__global__ void pack_kernel(const float* __restrict__ wq, const float* __restrict__ bq,
                            const float* __restrict__ wk, const float* __restrict__ bk,
                            const float* __restrict__ w1, int w1off,
                            float* __restrict__ wp, float* __restrict__ bias,
                            int C, int d) {
    int r = blockIdx.x;
    int tid = threadIdx.x;
    float* dst = wp + r * C;
    if (r < d) {
        for (int c = tid; c < C; c += blockDim.x) dst[c] = wq[r * C + c];
        if (tid == 0) bias[r] = bq[r];
    } else if (r < 2 * d) {
        int rr = r - d;
        for (int c = tid; c < C; c += blockDim.x) dst[c] = wk[rr * C + c];
        if (tid == 0) bias[r] = bk[rr];
    } else if (r == 2 * d) {
        return;  // filled by u_kernel
    } else {
        int j = r - (2 * d + 1);
        for (int c = tid; c < C; c += blockDim.x) dst[c] = w1[j * 896 + w1off + c];
        if (tid == 0) bias[r] = 0.f;
    }
}

// --------------------------- u = wa^T wv (parallel) ------------------------
__global__ void u_kernel(const float* __restrict__ wv, const float* __restrict__ wa,
                         const float* __restrict__ bv,
                         float* __restrict__ urow, float* __restrict__ ubias, int C) {
    __shared__ float red[256];
    int tid = threadIdx.x;
    int lci = tid & 63;
    int strip = tid >> 6;
    int ci = blockIdx.x * 64 + lci;
    float acc = 0.f;
#pragma unroll 4
    for (int co = strip; co < C; co += 4)
        acc += wa[co] * wv[co * C + ci];
    red[tid] = acc;
    __syncthreads();
    if (strip == 0)
        urow[ci] = red[lci] + red[lci + 64] + red[lci + 128] + red[lci + 192];
    if (blockIdx.x == 0) {
        __syncthreads();
        float bacc = 0.f;
        for (int co = tid; co < C; co += 256) bacc += wa[co] * bv[co];
        red[tid] = bacc;
        __syncthreads();
        for (int off = 128; off > 0; off >>= 1) {
            if (tid < off) red[tid] += red[tid + off];
            __syncthreads();
        }
        if (tid == 0) *ubias = red[0];
    }
}

// --------------------------- projection GEMM -------------------------------
__global__ __launch_bounds__(256) void proj_kernel(const float* __restrict__ x,
                                                   const float* __restrict__ wp,
                                                   const float* __restrict__ bias,
                                                   float* __restrict__ out,
                                                   int C, int Ns, int R) {
    __shared__ float Wl[8 * 512];
    __shared__ float bl[8];
    int b = blockIdx.z;
    int r0 = blockIdx.y * 8;
    int nr = min(8, R - r0);
    int tid = threadIdx.x;
    for (int rr = 0; rr < nr; ++rr)
        for (int c = tid; c < C; c += 256) Wl[rr * C + c] = wp[(r0 + rr) * C + c];
    if (tid < nr) bl[tid] = bias[r0 + tid];
    __syncthreads();
    int m = blockIdx.x * 256 + tid;
    float acc[8];
#pragma unroll
    for (int rr = 0; rr < 8; ++rr) acc[rr] = 0.f;
    const float* xb = x + (b * C) * Ns + m;
    for (int c = 0; c < C; ++c) {
        float xv = xb[c * Ns];
#pragma unroll
        for (int rr = 0; rr < 8; ++rr) acc[rr] += Wl[rr * C + c] * xv;
    }
    for (int rr = 0; rr < nr; ++rr)
        out[(b * R + r0 + rr) * Ns + m] = acc[rr] + bl[rr];
}

// --------------------------- upsample rows to 64x64 ------------------------
// proj pre-offset by r0*Ns; b-stride Rsrc*Ns.
__global__ void upsample_kernel(const float* __restrict__ proj, float* __restrict__ big,
                                int Rsrc, int nrows, int hs, int Ns) {
    int idx = blockIdx.x * 256 + threadIdx.x;
    int total = BB * nrows * 4096;
    if (idx >= total) return;
    int n = idx & 4095;
    int row = (idx >> 12) % nrows;
    int b = idx / (nrows * 4096);
    int oy = n >> 6, ox = n & 63;
    float f = (float)(hs - 1) / 63.0f;
    float cy = oy * f, cx = ox * f;
    int iy0 = min((int)floorf(cy), hs - 2);
    int ix0 = min((int)floorf(cx), hs - 2);
    float wy = cy - iy0, wx = cx - ix0;
    const float* ps = proj + (b * Rsrc + row) * Ns;
    float v00 = ps[iy0 * hs + ix0], v01 = ps[iy0 * hs + ix0 + 1];
    float v10 = ps[(iy0 + 1) * hs + ix0], v11 = ps[(iy0 + 1) * hs + ix0 + 1];
    float v = (1.f - wy) * ((1.f - wx) * v00 + wx * v01) + wy * ((1.f - wx) * v10 + wx * v11);
    big[(b * nrows + row) * 4096 + n] = v;
}

// --------------------------- phase A: native logits ------------------------
// lnat[b][ms (Ns)][n (npart)] = sum_dd qbig[b][dd][nbase+n] * k_nat[b][dd][ms]
// mpart[b][ms-tile][n] = per-tile max. NB=2 (n and n+256). K tile in LDS.
template <int D>
__global__ __launch_bounds__(256) void logits_kernel(const float* __restrict__ qbig,
                                                     const float* __restrict__ proj,
                                                     int R, int Ns,
                                                     float* __restrict__ lnat,
                                                     float* __restrict__ mpart,
                                                     int npart, int nbase) {
    constexpr int KS = D + 4;  // pad: conflict-lite writes, 16B-aligned float4 reads
    __shared__ __align__(16) float kl[32 * KS];
    int tid = threadIdx.x;
    int b = blockIdx.z;
    int ms0 = blockIdx.y * 32;
    int n_l = blockIdx.x * 512 + tid;
    int n_g = nbase + n_l;
    const float* kbase = proj + ((size_t)b * R + D) * Ns + ms0;
    for (int i = tid; i < 32 * D; i += 256) {
        int ms = i & 31;
        int dd = i >> 5;
        kl[ms * KS + dd] = kbase[(size_t)dd * Ns + ms];
    }
    __syncthreads();
    float acc0[32], acc1[32];
#pragma unroll
    for (int ms = 0; ms < 32; ++ms) { acc0[ms] = 0.f; acc1[ms] = 0.f; }
    const float* qp = qbig + (size_t)b * D * 4096 + n_g;
    for (int dd = 0; dd < D; dd += 4) {
        float qa0 = qp[(size_t)(dd + 0) * 4096];
        float qb0 = qp[(size_t)(dd + 1) * 4096];
        float qc0 = qp[(size_t)(dd + 2) * 4096];
        float qd0 = qp[(size_t)(dd + 3) * 4096];
        float qa1 = qp[(size_t)(dd + 0) * 4096 + 256];
        float qb1 = qp[(size_t)(dd + 1) * 4096 + 256];
        float qc1 = qp[(size_t)(dd + 2) * 4096 + 256];
        float qd1 = qp[(size_t)(dd + 3) * 4096 + 256];
#pragma unroll
        for (int ms = 0; ms < 32; ++ms) {
            float4 kv = *(const float4*)&kl[ms * KS + dd];
            acc0[ms] += qa0 * kv.x + qb0 * kv.y + qc0 * kv.z + qd0 * kv.w;
            acc1[ms] += qa1 * kv.x + qb1 * kv.y + qc1 * kv.z + qd1 * kv.w;
        }
    }
    float m0 = -1e30f, m1 = -1e30f;
#pragma unroll
    for (int ms = 0; ms < 32; ++ms) {
        lnat[((size_t)b * Ns + ms0 + ms) * npart + n_l] = acc0[ms];
        lnat[((size_t)b * Ns + ms0 + ms) * npart + n_l + 256] = acc1[ms];
        m0 = fmaxf(m0, acc0[ms]);
        m1 = fmaxf(m1, acc1[ms]);
    }
    mpart[((size_t)b * (Ns / 32) + blockIdx.y) * npart + n_l] = m0;
    mpart[((size_t)b * (Ns / 32) + blockIdx.y) * npart + n_l + 256] = m1;
}

// --------------------------- phase B: bilerp softmax-accumulate ------------
// Per thread: one n; 4 big rows (oy0..oy0+3); y-lerp native logit rows into
// Lr[HS] regs, fully-unrolled ox loop (compile-time ix0/wx); e=exp(v-M).
template <int HS>
__global__ __launch_bounds__(256) void attnb_kernel(const float* __restrict__ lnat,
                                                    const float* __restrict__ mpart,
                                                    const float* __restrict__ sbig,
                                                    float* __restrict__ pM,
                                                    float* __restrict__ pSn,
                                                    float* __restrict__ pSw,
                                                    int npart, int nbase) {
    constexpr int NS = HS * HS;
    constexpr int NT = NS / 32;
    constexpr float f = (float)(HS - 1) / 63.0f;
    __shared__ __align__(16) float sl[256];
    int tid = threadIdx.x;
    int b = blockIdx.z;
    int oy0 = blockIdx.y * 4;
    int n_l = blockIdx.x * 256 + tid;
    int n_g = nbase + n_l;
    sl[tid] = sbig[b * 4096 + oy0 * 64 + tid];
    __syncthreads();
    float M = -1e30f;
#pragma unroll
    for (int t = 0; t < NT; ++t)
        M = fmaxf(M, mpart[((size_t)b * NT + t) * npart + n_l]);
    float Sn = 0.f, Sw = 0.f;
    const float* lb = lnat + (size_t)b * NS * npart + n_l;
#pragma unroll
    for (int j = 0; j < 4; ++j) {
        int oy = oy0 + j;
        float cy = oy * f;
        int iy0 = min((int)cy, HS - 2);
        float wy = cy - (float)iy0;
        const float* r0 = lb + (size_t)(iy0 * HS) * npart;
        const float* r1 = r0 + (size_t)HS * npart;
        float Lr[HS];
#pragma unroll
        for (int ix = 0; ix < HS; ++ix) {
            float a = r0[(size_t)ix * npart];
            float c = r1[(size_t)ix * npart];
            Lr[ix] = a + wy * (c - a);
        }
#pragma unroll
        for (int ox4 = 0; ox4 < 64; ox4 += 4) {
            float4 sv = *(const float4*)&sl[j * 64 + ox4];
            float svv[4] = {sv.x, sv.y, sv.z, sv.w};
#pragma unroll
            for (int s4 = 0; s4 < 4; ++s4) {
                int ox = ox4 + s4;
                float cx = ox * f;
                int ix0 = min((int)cx, HS - 2);
                float wx = cx - (float)ix0;
                float v = Lr[ix0] + wx * (Lr[ix0 + 1] - Lr[ix0]);
                float e = __expf(v - M);
                Sn += e;
                Sw += e * svv[s4];
            }
        }
    }
    int pidx = (b * NC + blockIdx.y) * 4096 + n_g;
    pM[pidx] = M; pSn[pidx] = Sn; pSw[pidx] = Sw;
}

// --------------------------- scale2 flash attention (NB=4) -----------------
template <int D, int NB>
__global__ __launch_bounds__(256) void attn2_kernel(const float* __restrict__ base, int R,
                                                    float* __restrict__ pM,
                                                    float* __restrict__ pSn,
                                                    float* __restrict__ pSw) {
    __shared__ __align__(16) float kl[D * 128];
    __shared__ __align__(16) float sl[128];
    int tid = threadIdx.x;
    int b = blockIdx.z;
    int chunk = blockIdx.y;
    int n0 = blockIdx.x * (256 * NB) + tid;
    const float* bb = base + (size_t)b * R * 4096;
    float qv[NB][D];
#pragma unroll
    for (int i = 0; i < NB; ++i)
#pragma unroll
        for (int dd = 0; dd < D; ++dd)
            qv[i][dd] = bb[(size_t)dd * 4096 + n0 + i * 256];
    float M[NB], Sn[NB], Sw[NB];
#pragma unroll
    for (int i = 0; i < NB; ++i) { M[i] = -1e30f; Sn[i] = 0.f; Sw[i] = 0.f; }
    int m0 = chunk * 256;
    for (int mt = 0; mt < 256; mt += 128) {
        __syncthreads();
        int mbase = m0 + mt;
        constexpr int NF4 = D * 128 / 4;
        for (int fi = tid; fi < NF4; fi += 256) {
            int dd = fi >> 5;
            int mm = (fi << 2) & 127;
            *(float4*)&kl[dd * 128 + mm] = *(const float4*)&bb[(size_t)(D + dd) * 4096 + mbase + mm];
        }
        if (tid < 32)
            *(float4*)&sl[tid * 4] = *(const float4*)&bb[(size_t)(2 * D) * 4096 + mbase + tid * 4];
        __syncthreads();
        for (int mm = 0; mm < 128; mm += 4) {
            float l[NB][4];
#pragma unroll
            for (int i = 0; i < NB; ++i) { l[i][0] = 0.f; l[i][1] = 0.f; l[i][2] = 0.f; l[i][3] = 0.f; }
#pragma unroll
            for (int dd = 0; dd < D; ++dd) {
                float4 kv = *(const float4*)&kl[dd * 128 + mm];
#pragma unroll
                for (int i = 0; i < NB; ++i) {
                    float q = qv[i][dd];
                    l[i][0] += q * kv.x; l[i][1] += q * kv.y;
                    l[i][2] += q * kv.z; l[i][3] += q * kv.w;
                }
            }
            float4 sv = *(const float4*)&sl[mm];
#pragma unroll
            for (int i = 0; i < NB; ++i) {
                float lm = fmaxf(fmaxf(l[i][0], l[i][1]), fmaxf(l[i][2], l[i][3]));
                float Mn = fmaxf(M[i], lm);
                float sc = __expf(M[i] - Mn);
                float e0 = __expf(l[i][0] - Mn), e1 = __expf(l[i][1] - Mn);
                float e2 = __expf(l[i][2] - Mn), e3 = __expf(l[i][3] - Mn);
                Sn[i] = Sn[i] * sc + e0 + e1 + e2 + e3;
                Sw[i] = Sw[i] * sc + e0 * sv.x + e1 * sv.y + e2 * sv.z + e3 * sv.w;
                M[i] = Mn;
            }
        }
    }
#pragma unroll
    for (int i = 0; i < NB; ++i) {
        int pidx = (b * NC + chunk) * 4096 + n0 + i * 256;
        pM[pidx] = M[i]; pSn[pidx] = Sn[i]; pSw[pidx] = Sw[i];
    }
}

// --------------------------- combine partials ------------------------------
__global__ void combine_kernel(const float* __restrict__ pMb, const float* __restrict__ pSnb,
                               const float* __restrict__ pSwb,
                               const float* __restrict__ ba0, const float* __restrict__ ba1,
                               const float* __restrict__ ba2, float* __restrict__ a) {
    int s = blockIdx.y;
    const float* pM = pMb + s * PS;
    const float* pSn = pSnb + s * PS;
    const float* pSw = pSwb + s * PS;
    const float* bap = (s == 0) ? ba0 : (s == 1) ? ba1 : ba2;
    int idx = blockIdx.x * 256 + threadIdx.x;  // b*4096+n
    int b = idx >> 12, n = idx & 4095;
    float M = -1e30f;
#pragma unroll
    for (int ch = 0; ch < NC; ++ch) M = fmaxf(M, pM[(b * NC + ch) * 4096 + n]);
    float Sn = 0.f, Sw = 0.f;
#pragma unroll
    for (int ch = 0; ch < NC; ++ch) {
        int pi = (b * NC + ch) * 4096 + n;
        float sc = __expf(pM[pi] - M);
        Sn += pSn[pi] * sc;
        Sw += pSw[pi] * sc;
    }
    a[s * BB * 4096 + idx] = Sw / Sn + bap[0];
}

// --------------------------- final fusion ----------------------------------
__global__ __launch_bounds__(256) void final_kernel(const float* __restrict__ proj0,
                                                    const float* __restrict__ proj1,
                                                    const float* __restrict__ proj2,
                                                    const float* __restrict__ a,
                                                    const float* __restrict__ b1,
                                                    const float* __restrict__ w2,
                                                    const float* __restrict__ b2,
                                                    float* __restrict__ out) {
    __shared__ float lb1[32], lw2[32];
    int tid = threadIdx.x;
    if (tid < 32) { lb1[tid] = b1[tid]; lw2[tid] = w2[tid]; }
    __syncthreads();
    int b = blockIdx.y;
    int n = blockIdx.x * 256 + tid;
    int oy = n >> 6, ox = n & 63;
    float prod = a[(0 * BB + b) * 4096 + n] * a[(1 * BB + b) * 4096 + n] *
                 a[(2 * BB + b) * 4096 + n];
    float f0 = 15.0f / 63.0f;
    float cy0 = oy * f0, cx0 = ox * f0;
    int iy0 = min((int)floorf(cy0), 14), ix0 = min((int)floorf(cx0), 14);
    float wy0 = cy0 - iy0, wx0 = cx0 - ix0;
    float f1 = 31.0f / 63.0f;
    float cy1 = oy * f1, cx1 = ox * f1;
    int iy1 = min((int)floorf(cy1), 30), ix1 = min((int)floorf(cx1), 30);
    float wy1 = cy1 - iy1, wx1 = cx1 - ix1;
    const float* g0b = proj0 + (b * 161 + 129) * 256;
    const float* g1b = proj1 + (b * 97 + 65) * 1024;
    const float* g2b = proj2 + (b * 65 + 33) * 4096;
    float outv = 0.f;
    for (int j = 0; j < 32; ++j) {
        const float* p0 = g0b + j * 256;
        float v0 = (1.f - wy0) * ((1.f - wx0) * p0[iy0 * 16 + ix0] + wx0 * p0[iy0 * 16 + ix0 + 1]) +
                   wy0 * ((1.f - wx0) * p0[(iy0 + 1) * 16 + ix0] + wx0 * p0[(iy0 + 1) * 16 + ix0 + 1]);
        const float* p1 = g1b + j * 1024;
        float v1 = (1.f - wy1) * ((1.f - wx1) * p1[iy1 * 32 + ix1] + wx1 * p1[iy1 * 32 + ix1 + 1]) +
                   wy1 * ((1.f - wx1) * p1[(iy1 + 1) * 32 + ix1] + wx1 * p1[(iy1 + 1) * 32 + ix1 + 1]);
        float g = g2b[j * 4096 + n] + v0 + v1;
        float h = fmaxf(prod * g + lb1[j], 0.f);
        outv += lw2[j] * h;
    }
    out[b * 4096 + n] = outv + b2[0];
}

// ---------------------------------------------------------------------------
extern "C" void kernel_launch(void* const* d_in, const int* in_sizes, int n_in,
                              void* d_out, int out_size, void* d_ws, size_t ws_size,
                              hipStream_t stream) {
    const float* x3 = (const float*)d_in[0];
    const float* x2 = (const float*)d_in[1];
    const float* x1 = (const float*)d_in[2];
    const float* wq[3]; const float* bq[3]; const float* wk[3]; const float* bk[3];
    const float* wv[3]; const float* bv[3]; const float* wa[3]; const float* ba[3];
    for (int i = 0; i < 3; ++i) {
        wq[i] = (const float*)d_in[3 + 8 * i + 0];
        bq[i] = (const float*)d_in[3 + 8 * i + 1];
        wk[i] = (const float*)d_in[3 + 8 * i + 2];
        bk[i] = (const float*)d_in[3 + 8 * i + 3];
        wv[i] = (const float*)d_in[3 + 8 * i + 4];
        bv[i] = (const float*)d_in[3 + 8 * i + 5];
        wa[i] = (const float*)d_in[3 + 8 * i + 6];
        ba[i] = (const float*)d_in[3 + 8 * i + 7];
    }
    const float* w1 = (const float*)d_in[27];
    const float* b1 = (const float*)d_in[28];
    const float* w2 = (const float*)d_in[29];
    const float* b2 = (const float*)d_in[30];
    float* ws = (float*)d_ws;
    float* out = (float*)d_out;

    // pack q/k/w1 rows + u rows
    pack_kernel<<<161, 256, 0, stream>>>(wq[0], bq[0], wk[0], bk[0],
                                         w1, 384, ws + OFF_WP0, ws + OFF_B0, 512, 64);
    pack_kernel<<<97, 256, 0, stream>>>(wq[1], bq[1], wk[1], bk[1],
                                        w1, 128, ws + OFF_WP1, ws + OFF_B1, 256, 32);
    pack_kernel<<<65, 256, 0, stream>>>(wq[2], bq[2], wk[2], bk[2],
                                        w1, 0, ws + OFF_WP2, ws + OFF_B2, 128, 16);
    u_kernel<<<8, 256, 0, stream>>>(wv[0], wa[0], bv[0],
                                    ws + OFF_WP0 + 128 * 512, ws + OFF_B0 + 128, 512);
    u_kernel<<<4, 256, 0, stream>>>(wv[1], wa[1], bv[1],
                                    ws + OFF_WP1 + 64 * 256, ws + OFF_B1 + 64, 256);
    u_kernel<<<2, 256, 0, stream>>>(wv[2], wa[2], bv[2],
                                    ws + OFF_WP2 + 32 * 128, ws + OFF_B2 + 32, 128);

    // projection GEMMs at native resolution
    proj_kernel<<<dim3(1, 21, BB), 256, 0, stream>>>(x1, ws + OFF_WP0, ws + OFF_B0,
                                                     ws + OFF_PROJ0, 512, 256, 161);
    proj_kernel<<<dim3(4, 13, BB), 256, 0, stream>>>(x2, ws + OFF_WP1, ws + OFF_B1,
                                                     ws + OFF_PROJ1, 256, 1024, 97);
    proj_kernel<<<dim3(16, 9, BB), 256, 0, stream>>>(x3, ws + OFF_WP2, ws + OFF_B2,
                                                     ws + OFF_PROJ2, 128, 4096, 65);

    // upsample q + s rows only
    upsample_kernel<<<(BB * 64 * 4096) / 256, 256, 0, stream>>>(
        ws + OFF_PROJ0, ws + OFF_BIGQ0, 161, 64, 16, 256);
    upsample_kernel<<<(BB * 1 * 4096) / 256, 256, 0, stream>>>(
        ws + OFF_PROJ0 + 128 * 256, ws + OFF_SBIG0, 161, 1, 16, 256);
    upsample_kernel<<<(BB * 32 * 4096) / 256, 256, 0, stream>>>(
        ws + OFF_PROJ1, ws + OFF_BIGQ1, 97, 32, 32, 1024);
    upsample_kernel<<<(BB * 1 * 4096) / 256, 256, 0, stream>>>(
        ws + OFF_PROJ1 + 64 * 1024, ws + OFF_SBIG1, 97, 1, 32, 1024);

    // scale0: phase A then phase B (full n)
    logits_kernel<64><<<dim3(8, 8, BB), 256, 0, stream>>>(
        ws + OFF_BIGQ0, ws + OFF_PROJ0, 161, 256, ws + OFF_LNAT, ws + OFF_MPART, 4096, 0);
    attnb_kernel<16><<<dim3(16, 16, BB), 256, 0, stream>>>(
        ws + OFF_LNAT, ws + OFF_MPART, ws + OFF_SBIG0,
        ws + OFF_PM + 0 * PS, ws + OFF_PSN + 0 * PS, ws + OFF_PSW + 0 * PS, 4096, 0);

    // scale1: phase A/B per n-quarter (LNAT buffer reused sequentially)
    for (int q = 0; q < 4; ++q) {
        logits_kernel<32><<<dim3(2, 32, BB), 256, 0, stream>>>(
            ws + OFF_BIGQ1, ws + OFF_PROJ1, 97, 1024, ws + OFF_LNAT, ws + OFF_MPART,
            1024, q * 1024);
        attnb_kernel<32><<<dim3(4, 16, BB), 256, 0, stream>>>(
            ws + OFF_LNAT, ws + OFF_MPART, ws + OFF_SBIG1,
            ws + OFF_PM + 1 * PS, ws + OFF_PSN + 1 * PS, ws + OFF_PSW + 1 * PS,
            1024, q * 1024);
    }

    // scale2: flash attention NB=4
    attn2_kernel<16, 4><<<dim3(4, NC, BB), 256, 0, stream>>>(
        ws + OFF_PROJ2, 65, ws + OFF_PM + 2 * PS, ws + OFF_PSN + 2 * PS, ws + OFF_PSW + 2 * PS);

    // combine partials -> a[s][b][n] (+ba)
    combine_kernel<<<dim3(64, 3), 256, 0, stream>>>(ws + OFF_PM, ws + OFF_PSN, ws + OFF_PSW,
                                                    ba[0], ba[1], ba[2], ws + OFF_A);

    // final fusion
    final_kernel<<<dim3(16, BB), 256, 0, stream>>>(ws + OFF_PROJ0, ws + OFF_PROJ1, ws + OFF_PROJ2,
                                                   ws + OFF_A, b1, w2, b2, out);
}

// Round 4
// 442.358 us; speedup vs baseline: 1.5178x; 1.5178x over previous
//
#include <hip/hip_runtime.h>

// ---------------------------------------------------------------------------
// MultiScaleFeatureFusion — R4: 7-dispatch pipeline.
//   scale0: x1 [4,512,16,16]  d=64 C=512 hs=16 Ns=256
//   scale1: x2 [4,256,32,32]  d=32 C=256 hs=32 Ns=1024
//   scale2: x3 [4,128,64,64]  d=16 C=128 hs=64 Ns=4096
// prep (pack W + u=wa^T wv) -> proj (native GEMMs) -> upsample s rows ->
// attnf s0/s1 (fused native-logit rows + bilerp softmax, k via scalar loads)
// -> attn2 (flash, scalar k, no LDS) -> final (combine partials + fusion).
// ---------------------------------------------------------------------------

#define BB 4

static constexpr int OFF_WP0 = 0;                       // 161*512
static constexpr int OFF_WP1 = OFF_WP0 + 161 * 512;
static constexpr int OFF_WP2 = OFF_WP1 + 97 * 256;
static constexpr int OFF_B0  = OFF_WP2 + 65 * 128;
static constexpr int OFF_B1  = OFF_B0 + 192;
static constexpr int OFF_B2  = OFF_B1 + 128;
static constexpr int OFF_PROJ0 = OFF_B2 + 96;
static constexpr int OFF_PROJ1 = OFF_PROJ0 + BB * 161 * 256;
static constexpr int OFF_PROJ2 = OFF_PROJ1 + BB * 97 * 1024;
static constexpr int OFF_SBIG0 = OFF_PROJ2 + BB * 65 * 4096;   // [b][4096]
static constexpr int OFF_SBIG1 = OFF_SBIG0 + BB * 4096;        // [b][4096]
static constexpr int PSS = BB * 32 * 4096;                     // partial stride/scale
static constexpr int OFF_PM  = OFF_SBIG1 + BB * 4096;
static constexpr int OFF_PSN = OFF_PM + 3 * PSS;
static constexpr int OFF_PSW = OFF_PSN + 3 * PSS;              // total ~6.5M floats

// --------------------------- prep: pack + u --------------------------------
struct PrepArgs {
    const float *wq0, *bq0, *wk0, *bk0, *wv0, *bv0, *wa0;
    const float *wq1, *bq1, *wk1, *bk1, *wv1, *bv1, *wa1;
    const float *wq2, *bq2, *wk2, *bk2, *wv2, *bv2, *wa2;
    const float *w1;
    float *ws;
};

__global__ void prep_kernel(PrepArgs A) {
    __shared__ float red[256];
    int idx = blockIdx.x, tid = threadIdx.x;
    if (idx < 323) {
        int r, C, d, w1off;
        const float *wq, *bq, *wk, *bk;
        float *wp, *bias;
        if (idx < 161) {
            r = idx; C = 512; d = 64; w1off = 384;
            wq = A.wq0; bq = A.bq0; wk = A.wk0; bk = A.bk0;
            wp = A.ws + OFF_WP0; bias = A.ws + OFF_B0;
        } else if (idx < 258) {
            r = idx - 161; C = 256; d = 32; w1off = 128;
            wq = A.wq1; bq = A.bq1; wk = A.wk1; bk = A.bk1;
            wp = A.ws + OFF_WP1; bias = A.ws + OFF_B1;
        } else {
            r = idx - 258; C = 128; d = 16; w1off = 0;
            wq = A.wq2; bq = A.bq2; wk = A.wk2; bk = A.bk2;
            wp = A.ws + OFF_WP2; bias = A.ws + OFF_B2;
        }
        float* dst = wp + r * C;
        if (r < d) {
            for (int c = tid; c < C; c += 256) dst[c] = wq[r * C + c];
            if (tid == 0) bias[r] = bq[r];
        } else if (r < 2 * d) {
            int rr = r - d;
            for (int c = tid; c < C; c += 256) dst[c] = wk[rr * C + c];
            if (tid == 0) bias[r] = bk[rr];
        } else if (r > 2 * d) {
            int j = r - (2 * d + 1);
            for (int c = tid; c < C; c += 256) dst[c] = A.w1[j * 896 + w1off + c];
            if (tid == 0) bias[r] = 0.f;
        }
    } else {
        int ub = idx - 323;
        int lb, C;
        const float *wv, *wa, *bv;
        float *urow, *ubias;
        if (ub < 8) {
            lb = ub; C = 512; wv = A.wv0; wa = A.wa0; bv = A.bv0;
            urow = A.ws + OFF_WP0 + 128 * 512; ubias = A.ws + OFF_B0 + 128;
        } else if (ub < 12) {
            lb = ub - 8; C = 256; wv = A.wv1; wa = A.wa1; bv = A.bv1;
            urow = A.ws + OFF_WP1 + 64 * 256; ubias = A.ws + OFF_B1 + 64;
        } else {
            lb = ub - 12; C = 128; wv = A.wv2; wa = A.wa2; bv = A.bv2;
            urow = A.ws + OFF_WP2 + 32 * 128; ubias = A.ws + OFF_B2 + 32;
        }
        int lci = tid & 63, strip = tid >> 6;
        int ci = lb * 64 + lci;
        float acc = 0.f;
        for (int co = strip; co < C; co += 4) acc += wa[co] * wv[co * C + ci];
        red[tid] = acc;
        __syncthreads();
        if (strip == 0)
            urow[ci] = red[lci] + red[lci + 64] + red[lci + 128] + red[lci + 192];
        if (lb == 0) {
            __syncthreads();
            float bacc = 0.f;
            for (int co = tid; co < C; co += 256) bacc += wa[co] * bv[co];
            red[tid] = bacc;
            __syncthreads();
            for (int off = 128; off > 0; off >>= 1) {
                if (tid < off) red[tid] += red[tid + off];
                __syncthreads();
            }
            if (tid == 0) *ubias = red[0];
        }
    }
}

// --------------------------- proj: all scales ------------------------------
struct ProjArgs { const float *x0, *x1, *x2; float* ws; };

__global__ __launch_bounds__(256) void proj_kernel(ProjArgs A) {
    __shared__ float Wl[8 * 512];
    __shared__ float bl[8];
    int idx = blockIdx.x, tid = threadIdx.x;
    const float *x, *wp, *bias;
    float* out;
    int C, Ns, R, nx, local;
    if (idx < 84) {
        local = idx; x = A.x0; wp = A.ws + OFF_WP0; bias = A.ws + OFF_B0;
        out = A.ws + OFF_PROJ0; C = 512; Ns = 256; R = 161; nx = 1;
    } else if (idx < 292) {
        local = idx - 84; x = A.x1; wp = A.ws + OFF_WP1; bias = A.ws + OFF_B1;
        out = A.ws + OFF_PROJ1; C = 256; Ns = 1024; R = 97; nx = 4;
    } else {
        local = idx - 292; x = A.x2; wp = A.ws + OFF_WP2; bias = A.ws + OFF_B2;
        out = A.ws + OFF_PROJ2; C = 128; Ns = 4096; R = 65; nx = 16;
    }
    int ny = (R + 7) >> 3;
    int pb = nx * ny;
    int b = local / pb;
    int rem = local - b * pb;
    int by = rem / nx;
    int bx = rem - by * nx;
    int r0 = by * 8;
    int nr = min(8, R - r0);
    for (int rr = 0; rr < nr; ++rr)
        for (int c = tid; c < C; c += 256) Wl[rr * C + c] = wp[(r0 + rr) * C + c];
    if (tid < nr) bl[tid] = bias[r0 + tid];
    __syncthreads();
    int m = bx * 256 + tid;
    float acc[8];
#pragma unroll
    for (int rr = 0; rr < 8; ++rr) acc[rr] = 0.f;
    const float* xb = x + (size_t)(b * C) * Ns + m;
    for (int c = 0; c < C; ++c) {
        float xv = xb[(size_t)c * Ns];
#pragma unroll
        for (int rr = 0; rr < 8; ++rr) acc[rr] += Wl[rr * C + c] * xv;
    }
    for (int rr = 0; rr < nr; ++rr)
        out[(size_t)(b * R + r0 + rr) * Ns + m] = acc[rr] + bl[rr];
}

// --------------------------- upsample s rows -------------------------------
__global__ void upsample_s_kernel(float* ws) {
    int idx = blockIdx.x * 256 + threadIdx.x;  // 0..32767
    int seg = idx >> 14;
    int li = idx & 16383;
    int b = li >> 12, n = li & 4095;
    const float* src;
    float* dst;
    int hs;
    if (seg == 0) { src = ws + OFF_PROJ0 + (b * 161 + 128) * 256;  dst = ws + OFF_SBIG0; hs = 16; }
    else          { src = ws + OFF_PROJ1 + (b * 97 + 64) * 1024;   dst = ws + OFF_SBIG1; hs = 32; }
    int oy = n >> 6, ox = n & 63;
    float f = (float)(hs - 1) / 63.0f;
    float cy = oy * f, cx = ox * f;
    int iy0 = min((int)cy, hs - 2);
    int ix0 = min((int)cx, hs - 2);
    float wy = cy - iy0, wx = cx - ix0;
    float v00 = src[iy0 * hs + ix0], v01 = src[iy0 * hs + ix0 + 1];
    float v10 = src[(iy0 + 1) * hs + ix0], v11 = src[(iy0 + 1) * hs + ix0 + 1];
    float t0 = v00 + wx * (v01 - v00), t1 = v10 + wx * (v11 - v10);
    dst[b * 4096 + n] = t0 + wy * (t1 - t0);
}

// --------------------------- fused attention (scales 0/1) ------------------
// Per block: 256 n-threads x 8 output rows (oy0..oy0+7). Native logit rows
// L[ms]=q_n.k_nat computed in registers (k via wave-uniform scalar loads),
// shifted as oy advances. v = bilerp(L rows); e=exp(v-M) with M = running
// max of row entries (valid bound: bilerp <= max of corners). q is bilerped
// from native proj on the fly. Partial (M,Sn,Sw) per 8-row chunk.
#define COMPUTE_ROW(dst, dstmax, iy)                                          \
    {                                                                         \
        const float* krow_ = kp + (size_t)(iy) * HS;                          \
        _Pragma("unroll") for (int ms = 0; ms < HS; ++ms) dst[ms] = 0.f;      \
        _Pragma("unroll") for (int dd_ = 0; dd_ < D; ++dd_) {                 \
            _Pragma("unroll") for (int ms = 0; ms < HS; ++ms)                 \
                dst[ms] += q[dd_] * krow_[(size_t)dd_ * NS + ms];             \
        }                                                                     \
        dstmax = -1e30f;                                                      \
        _Pragma("unroll") for (int ms = 0; ms < HS; ++ms)                     \
            dstmax = fmaxf(dstmax, dst[ms]);                                  \
    }

template <int D, int HS>
__global__ __launch_bounds__(256, 2) void attnf_kernel(const float* __restrict__ proj,
                                                       const float* __restrict__ sbig,
                                                       int R,
                                                       float* __restrict__ pM,
                                                       float* __restrict__ pSn,
                                                       float* __restrict__ pSw) {
    constexpr int NS = HS * HS;
    constexpr float f = (float)(HS - 1) / 63.0f;
    int tid = threadIdx.x;
    int b = blockIdx.z;
    int oy0 = blockIdx.y * 8;
    int n = blockIdx.x * 256 + tid;
    // q = bilerp of native q rows
    int noy = n >> 6, nox = n & 63;
    float cyq = noy * f, cxq = nox * f;
    int iyq = min((int)cyq, HS - 2), ixq = min((int)cxq, HS - 2);
    float wyq = cyq - iyq, wxq = cxq - ixq;
    const float* qb = proj + (size_t)b * R * NS + iyq * HS + ixq;
    float q[D];
#pragma unroll
    for (int dd = 0; dd < D; ++dd) {
        const float* p = qb + (size_t)dd * NS;
        float v00 = p[0], v01 = p[1], v10 = p[HS], v11 = p[HS + 1];
        float t0 = v00 + wxq * (v01 - v00);
        float t1 = v10 + wxq * (v11 - v10);
        q[dd] = t0 + wyq * (t1 - t0);
    }
    const float* kp = proj + ((size_t)b * R + D) * NS;
    const float* sp = sbig + b * 4096;
    float rA[HS], rB[HS], Lr[HS];
    float rmA = -1e30f, rmB = -1e30f;
    int iyA = -1000;
    float M = -1e30f, Sn = 0.f, Sw = 0.f;
    for (int j = 0; j < 8; ++j) {
        int oy = oy0 + j;
        float cy = oy * f;
        int iy0 = min((int)cy, HS - 2);
        float wy = cy - iy0;
        if (iy0 == iyA + 1) {
#pragma unroll
            for (int ms = 0; ms < HS; ++ms) rA[ms] = rB[ms];
            rmA = rmB;
            COMPUTE_ROW(rB, rmB, iy0 + 1)
            iyA = iy0;
        } else if (iy0 != iyA) {
            COMPUTE_ROW(rA, rmA, iy0)
            COMPUTE_ROW(rB, rmB, iy0 + 1)
            iyA = iy0;
        }
        float Mn = fmaxf(M, fmaxf(rmA, rmB));
        float sc = __expf(M - Mn);
        Sn *= sc; Sw *= sc; M = Mn;
#pragma unroll
        for (int ms = 0; ms < HS; ++ms) Lr[ms] = rA[ms] + wy * (rB[ms] - rA[ms]);
        const float* sj = sp + oy * 64;
#pragma unroll
        for (int ox = 0; ox < 64; ++ox) {
            float cx = ox * f;
            int ix0 = min((int)cx, HS - 2);
            float wx = cx - (float)ix0;
            float v = Lr[ix0] + wx * (Lr[ix0 + 1] - Lr[ix0]);
            float e = __expf(v - M);
            Sn += e;
            Sw += e * sj[ox];
        }
    }
    int pidx = (b * 32 + blockIdx.y) * 4096 + n;
    pM[pidx] = M; pSn[pidx] = Sn; pSw[pidx] = Sw;
}

// --------------------------- scale2 flash attention ------------------------
// No LDS, no barriers: k and s read via wave-uniform scalar loads. NB=4,
// 32 chunks of 128 m -> 512 blocks (2/CU).
template <int D, int NB>
__global__ __launch_bounds__(256) void attn2_kernel(const float* __restrict__ base,
                                                    float* __restrict__ pM,
                                                    float* __restrict__ pSn,
                                                    float* __restrict__ pSw) {
    int tid = threadIdx.x;
    int b = blockIdx.z, chunk = blockIdx.y;
    int n0 = blockIdx.x * (256 * NB) + tid;
    const float* bb = base + (size_t)b * 65 * 4096;
    const float* kp = bb + (size_t)D * 4096;
    const float* sp = bb + (size_t)(2 * D) * 4096;
    float qv[NB][D];
#pragma unroll
    for (int i = 0; i < NB; ++i)
#pragma unroll
        for (int dd = 0; dd < D; ++dd)
            qv[i][dd] = bb[(size_t)dd * 4096 + n0 + i * 256];
    float M[NB], Sn[NB], Sw[NB];
#pragma unroll
    for (int i = 0; i < NB; ++i) { M[i] = -1e30f; Sn[i] = 0.f; Sw[i] = 0.f; }
    int m0 = chunk * 128;
    for (int mm = 0; mm < 128; mm += 4) {
        float l[NB][4];
#pragma unroll
        for (int i = 0; i < NB; ++i) { l[i][0] = 0.f; l[i][1] = 0.f; l[i][2] = 0.f; l[i][3] = 0.f; }
#pragma unroll
        for (int dd = 0; dd < D; ++dd) {
            float4 kv = *(const float4*)&kp[(size_t)dd * 4096 + m0 + mm];
#pragma unroll
            for (int i = 0; i < NB; ++i) {
                float qq = qv[i][dd];
                l[i][0] += qq * kv.x; l[i][1] += qq * kv.y;
                l[i][2] += qq * kv.z; l[i][3] += qq * kv.w;
            }
        }
        float4 sv = *(const float4*)&sp[m0 + mm];
#pragma unroll
        for (int i = 0; i < NB; ++i) {
            float lm = fmaxf(fmaxf(l[i][0], l[i][1]), fmaxf(l[i][2], l[i][3]));
            float Mn = fmaxf(M[i], lm);
            float sc = __expf(M[i] - Mn);
            float e0 = __expf(l[i][0] - Mn), e1 = __expf(l[i][1] - Mn);
            float e2 = __expf(l[i][2] - Mn), e3 = __expf(l[i][3] - Mn);
            Sn[i] = Sn[i] * sc + e0 + e1 + e2 + e3;
            Sw[i] = Sw[i] * sc + e0 * sv.x + e1 * sv.y + e2 * sv.z + e3 * sv.w;
            M[i] = Mn;
        }
    }
#pragma unroll
    for (int i = 0; i < NB; ++i) {
        int pidx = (b * 32 + chunk) * 4096 + n0 + i * 256;
        pM[pidx] = M[i]; pSn[pidx] = Sn[i]; pSw[pidx] = Sw[i];
    }
}

// --------------------------- combine + final fusion ------------------------
__global__ __launch_bounds__(256) void final_kernel(const float* __restrict__ ws,
                                                    const float* __restrict__ ba0,
                                                    const float* __restrict__ ba1,
                                                    const float* __restrict__ ba2,
                                                    const float* __restrict__ b1,
                                                    const float* __restrict__ w2,
                                                    const float* __restrict__ b2,
                                                    float* __restrict__ out) {
    __shared__ float lb1[32], lw2[32];
    int tid = threadIdx.x;
    if (tid < 32) { lb1[tid] = b1[tid]; lw2[tid] = w2[tid]; }
    __syncthreads();
    int b = blockIdx.y;
    int n = blockIdx.x * 256 + tid;
    float a[3];
#pragma unroll
    for (int s = 0; s < 3; ++s) {
        int nc = (s == 2) ? 32 : 8;
        const float* pMs = ws + OFF_PM + s * PSS;
        const float* pSns = ws + OFF_PSN + s * PSS;
        const float* pSws = ws + OFF_PSW + s * PSS;
        float Mx = -1e30f;
        for (int ch = 0; ch < nc; ++ch)
            Mx = fmaxf(Mx, pMs[(b * 32 + ch) * 4096 + n]);
        float Sn = 0.f, Sw = 0.f;
        for (int ch = 0; ch < nc; ++ch) {
            int pi = (b * 32 + ch) * 4096 + n;
            float sc = __expf(pMs[pi] - Mx);
            Sn += pSns[pi] * sc;
            Sw += pSws[pi] * sc;
        }
        float bav = (s == 0) ? ba0[0] : (s == 1) ? ba1[0] : ba2[0];
        a[s] = Sw / Sn + bav;
    }
    float prod = a[0] * a[1] * a[2];
    int oy = n >> 6, ox = n & 63;
    float f0 = 15.0f / 63.0f;
    float cy0 = oy * f0, cx0 = ox * f0;
    int iy0 = min((int)cy0, 14), ix0 = min((int)cx0, 14);
    float wy0 = cy0 - iy0, wx0 = cx0 - ix0;
    float f1 = 31.0f / 63.0f;
    float cy1 = oy * f1, cx1 = ox * f1;
    int iy1 = min((int)cy1, 30), ix1 = min((int)cx1, 30);
    float wy1 = cy1 - iy1, wx1 = cx1 - ix1;
    const float* g0b = ws + OFF_PROJ0 + (b * 161 + 129) * 256;
    const float* g1b = ws + OFF_PROJ1 + (b * 97 + 65) * 1024;
    const float* g2b = ws + OFF_PROJ2 + (b * 65 + 33) * 4096;
    float outv = 0.f;
    for (int j = 0; j < 32; ++j) {
        const float* p0 = g0b + j * 256;
        float v0 = (1.f - wy0) * ((1.f - wx0) * p0[iy0 * 16 + ix0] + wx0 * p0[iy0 * 16 + ix0 + 1]) +
                   wy0 * ((1.f - wx0) * p0[(iy0 + 1) * 16 + ix0] + wx0 * p0[(iy0 + 1) * 16 + ix0 + 1]);
        const float* p1 = g1b + j * 1024;
        float v1 = (1.f - wy1) * ((1.f - wx1) * p1[iy1 * 32 + ix1] + wx1 * p1[iy1 * 32 + ix1 + 1]) +
                   wy1 * ((1.f - wx1) * p1[(iy1 + 1) * 32 + ix1] + wx1 * p1[(iy1 + 1) * 32 + ix1 + 1]);
        float g = g2b[j * 4096 + n] + v0 + v1;
        float h = fmaxf(prod * g + lb1[j], 0.f);
        outv += lw2[j] * h;
    }
    out[b * 4096 + n] = outv + b2[0];
}

// ---------------------------------------------------------------------------
extern "C" void kernel_launch(void* const* d_in, const int* in_sizes, int n_in,
                              void* d_out, int out_size, void* d_ws, size_t ws_size,
                              hipStream_t stream) {
    const float* x3 = (const float*)d_in[0];
    const float* x2 = (const float*)d_in[1];
    const float* x1 = (const float*)d_in[2];
    const float* W[24];
    for (int i = 0; i < 24; ++i) W[i] = (const float*)d_in[3 + i];
    // layout per scale i: wq,bq,wk,bk,wv,bv,wa,ba at W[8i..]
    const float* w1 = (const float*)d_in[27];
    const float* b1 = (const float*)d_in[28];
    const float* w2 = (const float*)d_in[29];
    const float* b2 = (const float*)d_in[30];
    float* ws = (float*)d_ws;
    float* out = (float*)d_out;

    PrepArgs pa;
    pa.wq0 = W[0];  pa.bq0 = W[1];  pa.wk0 = W[2];  pa.bk0 = W[3];
    pa.wv0 = W[4];  pa.bv0 = W[5];  pa.wa0 = W[6];
    pa.wq1 = W[8];  pa.bq1 = W[9];  pa.wk1 = W[10]; pa.bk1 = W[11];
    pa.wv1 = W[12]; pa.bv1 = W[13]; pa.wa1 = W[14];
    pa.wq2 = W[16]; pa.bq2 = W[17]; pa.wk2 = W[18]; pa.bk2 = W[19];
    pa.wv2 = W[20]; pa.bv2 = W[21]; pa.wa2 = W[22];
    pa.w1 = w1; pa.ws = ws;
    prep_kernel<<<337, 256, 0, stream>>>(pa);

    ProjArgs ja; ja.x0 = x1; ja.x1 = x2; ja.x2 = x3; ja.ws = ws;
    proj_kernel<<<868, 256, 0, stream>>>(ja);

    upsample_s_kernel<<<128, 256, 0, stream>>>(ws);

    attnf_kernel<64, 16><<<dim3(16, 8, BB), 256, 0, stream>>>(
        ws + OFF_PROJ0, ws + OFF_SBIG0, 161,
        ws + OFF_PM + 0 * PSS, ws + OFF_PSN + 0 * PSS, ws + OFF_PSW + 0 * PSS);
    attnf_kernel<32, 32><<<dim3(16, 8, BB), 256, 0, stream>>>(
        ws + OFF_PROJ1, ws + OFF_SBIG1, 97,
        ws + OFF_PM + 1 * PSS, ws + OFF_PSN + 1 * PSS, ws + OFF_PSW + 1 * PSS);
    attn2_kernel<16, 4><<<dim3(4, 32, BB), 256, 0, stream>>>(
        ws + OFF_PROJ2,
        ws + OFF_PM + 2 * PSS, ws + OFF_PSN + 2 * PSS, ws + OFF_PSW + 2 * PSS);

    final_kernel<<<dim3(16, BB), 256, 0, stream>>>(ws, W[7], W[15], W[23],
                                                   b1, w2, b2, out);
}

// Round 5
// 368.180 us; speedup vs baseline: 1.8237x; 1.2015x over previous
//
#include <hip/hip_runtime.h>

// ---------------------------------------------------------------------------
// MultiScaleFeatureFusion — R5.
//   scale0: x1 [4,512,16,16]  d=64 C=512 hs=16 Ns=256
//   scale1: x2 [4,256,32,32]  d=32 C=256 hs=32 Ns=1024
//   scale2: x3 [4,128,64,64]  d=16 C=128 hs=64 Ns=4096
// prep (pack W + u=wa^T wv) -> proj (native GEMMs, Wl transposed) ->
// upsample s rows -> lnat (native q^T k logit tables, scales 0/1) ->
// attnf (bilerp of L_nat both sides + online softmax; per-lane coalesced
// L_nat loads, s via LDS) -> attn2 (flash, LDS-staged k/s, NB=4, 512 blk)
// -> final (combine partials + fusion).
// ---------------------------------------------------------------------------

#define BB 4

static constexpr int OFF_WP0 = 0;                        // 161*512
static constexpr int OFF_WP1 = OFF_WP0 + 161 * 512;
static constexpr int OFF_WP2 = OFF_WP1 + 97 * 256;
static constexpr int OFF_B0  = OFF_WP2 + 65 * 128;
static constexpr int OFF_B1  = OFF_B0 + 192;
static constexpr int OFF_B2  = OFF_B1 + 128;
static constexpr int OFF_PROJ0 = OFF_B2 + 96;
static constexpr int OFF_PROJ1 = OFF_PROJ0 + BB * 161 * 256;
static constexpr int OFF_PROJ2 = OFF_PROJ1 + BB * 97 * 1024;
static constexpr int OFF_SBIG0 = OFF_PROJ2 + BB * 65 * 4096;   // [b][4096]
static constexpr int OFF_SBIG1 = OFF_SBIG0 + BB * 4096;        // [b][4096]
static constexpr int OFF_LN0   = OFF_SBIG1 + BB * 4096;        // [b][256][256]
static constexpr int OFF_LN1   = OFF_LN0 + BB * 256 * 256;     // [b][1024][1024]
static constexpr int PS01 = BB * 8 * 4096;
static constexpr int PS2  = BB * 32 * 4096;
static constexpr int OFF_PM0  = OFF_LN1 + BB * 1024 * 1024;
static constexpr int OFF_PSN0 = OFF_PM0 + PS01;
static constexpr int OFF_PSW0 = OFF_PSN0 + PS01;
static constexpr int OFF_PM1  = OFF_PSW0 + PS01;
static constexpr int OFF_PSN1 = OFF_PM1 + PS01;
static constexpr int OFF_PSW1 = OFF_PSN1 + PS01;
static constexpr int OFF_PM2  = OFF_PSW1 + PS01;
static constexpr int OFF_PSN2 = OFF_PM2 + PS2;
static constexpr int OFF_PSW2 = OFF_PSN2 + PS2;                // end ~8.6M floats

// --------------------------- prep: pack + u --------------------------------
struct PrepArgs {
    const float *wq0, *bq0, *wk0, *bk0, *wv0, *bv0, *wa0;
    const float *wq1, *bq1, *wk1, *bk1, *wv1, *bv1, *wa1;
    const float *wq2, *bq2, *wk2, *bk2, *wv2, *bv2, *wa2;
    const float *w1;
    float *ws;
};

__global__ void prep_kernel(PrepArgs A) {
    __shared__ float red[256];
    int idx = blockIdx.x, tid = threadIdx.x;
    if (idx < 323) {
        int r, C, d, w1off;
        const float *wq, *bq, *wk, *bk;
        float *wp, *bias;
        if (idx < 161) {
            r = idx; C = 512; d = 64; w1off = 384;
            wq = A.wq0; bq = A.bq0; wk = A.wk0; bk = A.bk0;
            wp = A.ws + OFF_WP0; bias = A.ws + OFF_B0;
        } else if (idx < 258) {
            r = idx - 161; C = 256; d = 32; w1off = 128;
            wq = A.wq1; bq = A.bq1; wk = A.wk1; bk = A.bk1;
            wp = A.ws + OFF_WP1; bias = A.ws + OFF_B1;
        } else {
            r = idx - 258; C = 128; d = 16; w1off = 0;
            wq = A.wq2; bq = A.bq2; wk = A.wk2; bk = A.bk2;
            wp = A.ws + OFF_WP2; bias = A.ws + OFF_B2;
        }
        float* dst = wp + r * C;
        if (r < d) {
            for (int c = tid; c < C; c += 256) dst[c] = wq[r * C + c];
            if (tid == 0) bias[r] = bq[r];
        } else if (r < 2 * d) {
            int rr = r - d;
            for (int c = tid; c < C; c += 256) dst[c] = wk[rr * C + c];
            if (tid == 0) bias[r] = bk[rr];
        } else if (r > 2 * d) {
            int j = r - (2 * d + 1);
            for (int c = tid; c < C; c += 256) dst[c] = A.w1[j * 896 + w1off + c];
            if (tid == 0) bias[r] = 0.f;
        }
    } else {
        int ub = idx - 323;
        int lb, C;
        const float *wv, *wa, *bv;
        float *urow, *ubias;
        if (ub < 8) {
            lb = ub; C = 512; wv = A.wv0; wa = A.wa0; bv = A.bv0;
            urow = A.ws + OFF_WP0 + 128 * 512; ubias = A.ws + OFF_B0 + 128;
        } else if (ub < 12) {
            lb = ub - 8; C = 256; wv = A.wv1; wa = A.wa1; bv = A.bv1;
            urow = A.ws + OFF_WP1 + 64 * 256; ubias = A.ws + OFF_B1 + 64;
        } else {
            lb = ub - 12; C = 128; wv = A.wv2; wa = A.wa2; bv = A.bv2;
            urow = A.ws + OFF_WP2 + 32 * 128; ubias = A.ws + OFF_B2 + 32;
        }
        int lci = tid & 63, strip = tid >> 6;
        int ci = lb * 64 + lci;
        float acc = 0.f;
        for (int co = strip; co < C; co += 4) acc += wa[co] * wv[co * C + ci];
        red[tid] = acc;
        __syncthreads();
        if (strip == 0)
            urow[ci] = red[lci] + red[lci + 64] + red[lci + 128] + red[lci + 192];
        if (lb == 0) {
            __syncthreads();
            float bacc = 0.f;
            for (int co = tid; co < C; co += 256) bacc += wa[co] * bv[co];
            red[tid] = bacc;
            __syncthreads();
            for (int off = 128; off > 0; off >>= 1) {
                if (tid < off) red[tid] += red[tid + off];
                __syncthreads();
            }
            if (tid == 0) *ubias = red[0];
        }
    }
}

// --------------------------- proj: all scales ------------------------------
struct ProjArgs { const float *x0, *x1, *x2; float* ws; };

__global__ __launch_bounds__(256) void proj_kernel(ProjArgs A) {
    __shared__ __align__(16) float Wl[512 * 8];   // transposed: [c][rr]
    __shared__ float bl[8];
    int idx = blockIdx.x, tid = threadIdx.x;
    const float *x, *wp, *bias;
    float* out;
    int C, Ns, R, nx, local;
    if (idx < 84) {
        local = idx; x = A.x0; wp = A.ws + OFF_WP0; bias = A.ws + OFF_B0;
        out = A.ws + OFF_PROJ0; C = 512; Ns = 256; R = 161; nx = 1;
    } else if (idx < 292) {
        local = idx - 84; x = A.x1; wp = A.ws + OFF_WP1; bias = A.ws + OFF_B1;
        out = A.ws + OFF_PROJ1; C = 256; Ns = 1024; R = 97; nx = 4;
    } else {
        local = idx - 292; x = A.x2; wp = A.ws + OFF_WP2; bias = A.ws + OFF_B2;
        out = A.ws + OFF_PROJ2; C = 128; Ns = 4096; R = 65; nx = 16;
    }
    int ny = (R + 7) >> 3;
    int pb = nx * ny;
    int b = local / pb;
    int rem = local - b * pb;
    int by = rem / nx;
    int bx = rem - by * nx;
    int r0 = by * 8;
    int nr = min(8, R - r0);
    for (int i = tid; i < C * 8; i += 256) {
        int rr = i & 7, c = i >> 3;
        Wl[i] = (rr < nr) ? wp[(r0 + rr) * C + c] : 0.f;
    }
    if (tid < nr) bl[tid] = bias[r0 + tid];
    __syncthreads();
    int m = bx * 256 + tid;
    float acc[8];
#pragma unroll
    for (int rr = 0; rr < 8; ++rr) acc[rr] = 0.f;
    const float* xb = x + (size_t)(b * C) * Ns + m;
#pragma unroll 4
    for (int c = 0; c < C; ++c) {
        float xv = xb[(size_t)c * Ns];
        float4 w0 = *(const float4*)&Wl[c * 8];
        float4 w1v = *(const float4*)&Wl[c * 8 + 4];
        acc[0] += w0.x * xv; acc[1] += w0.y * xv;
        acc[2] += w0.z * xv; acc[3] += w0.w * xv;
        acc[4] += w1v.x * xv; acc[5] += w1v.y * xv;
        acc[6] += w1v.z * xv; acc[7] += w1v.w * xv;
    }
    for (int rr = 0; rr < nr; ++rr)
        out[(size_t)(b * R + r0 + rr) * Ns + m] = acc[rr] + bl[rr];
}

// --------------------------- upsample s rows -------------------------------
__global__ void upsample_s_kernel(float* ws) {
    int idx = blockIdx.x * 256 + threadIdx.x;  // 0..32767
    int seg = idx >> 14;
    int li = idx & 16383;
    int b = li >> 12, n = li & 4095;
    const float* src;
    float* dst;
    int hs;
    if (seg == 0) { src = ws + OFF_PROJ0 + (b * 161 + 128) * 256;  dst = ws + OFF_SBIG0; hs = 16; }
    else          { src = ws + OFF_PROJ1 + (b * 97 + 64) * 1024;   dst = ws + OFF_SBIG1; hs = 32; }
    int oy = n >> 6, ox = n & 63;
    float f = (float)(hs - 1) / 63.0f;
    float cy = oy * f, cx = ox * f;
    int iy0 = min((int)cy, hs - 2);
    int ix0 = min((int)cx, hs - 2);
    float wy = cy - iy0, wx = cx - ix0;
    float v00 = src[iy0 * hs + ix0], v01 = src[iy0 * hs + ix0 + 1];
    float v10 = src[(iy0 + 1) * hs + ix0], v11 = src[(iy0 + 1) * hs + ix0 + 1];
    float t0 = v00 + wx * (v01 - v00), t1 = v10 + wx * (v11 - v10);
    dst[b * 4096 + n] = t0 + wy * (t1 - t0);
}

// --------------------------- native logit table ----------------------------
// L[b][ns][ms] = sum_dd q[dd][ns] * k[dd][ms]   (q: proj rows 0..D, k: D..2D)
template <int D, int NS>
__global__ __launch_bounds__(256) void lnat_kernel(const float* __restrict__ proj, int R,
                                                   float* __restrict__ L) {
    __shared__ __align__(16) float kl[D * 32];
    int tid = threadIdx.x;
    int b = blockIdx.z;
    int ms0 = blockIdx.y * 32;
    int ns = blockIdx.x * 256 + tid;
    const float* pb = proj + (size_t)b * R * NS;
    for (int i = tid; i < D * 8; i += 256) {
        int dd = i >> 3;
        int mm = (i & 7) * 4;
        *(float4*)&kl[dd * 32 + mm] = *(const float4*)&pb[(size_t)(D + dd) * NS + ms0 + mm];
    }
    __syncthreads();
    float acc[32];
#pragma unroll
    for (int j = 0; j < 32; ++j) acc[j] = 0.f;
    for (int dd = 0; dd < D; ++dd) {
        float qv = pb[(size_t)dd * NS + ns];
#pragma unroll
        for (int j = 0; j < 32; j += 4) {
            float4 kv = *(const float4*)&kl[dd * 32 + j];
            acc[j] += qv * kv.x; acc[j + 1] += qv * kv.y;
            acc[j + 2] += qv * kv.z; acc[j + 3] += qv * kv.w;
        }
    }
    float* dst = L + ((size_t)b * NS + ns) * NS + ms0;
#pragma unroll
    for (int j = 0; j < 32; j += 4)
        *(float4*)&dst[j] = make_float4(acc[j], acc[j + 1], acc[j + 2], acc[j + 3]);
}

// --------------------------- fused attention (scales 0/1) ------------------
// Thread = one big n; 8 output m-rows per block. Native m-logit rows built
// from 4 L_nat rows (q-side bilerp, 4 FMA/ms, per-lane coalesced float4
// loads), rows shifted/reused as oy advances; x/y bilerp + online softmax.
// M = running max of native row entries (valid: bilerp <= max of corners).
#define CROW(dst, dstmax, iy)                                                 \
    {                                                                         \
        int off_ = (iy) * HS;                                                 \
        dstmax = -1e30f;                                                      \
        _Pragma("unroll") for (int ms = 0; ms < HS; ms += 4) {                \
            float4 a_ = *(const float4*)&pA[off_ + ms];                       \
            float4 b_ = *(const float4*)&pB[off_ + ms];                       \
            float4 c_ = *(const float4*)&pC[off_ + ms];                       \
            float4 d_ = *(const float4*)&pD[off_ + ms];                       \
            float v0 = wA * a_.x + wB * b_.x + wC * c_.x + wD * d_.x;         \
            float v1 = wA * a_.y + wB * b_.y + wC * c_.y + wD * d_.y;         \
            float v2 = wA * a_.z + wB * b_.z + wC * c_.z + wD * d_.z;         \
            float v3 = wA * a_.w + wB * b_.w + wC * c_.w + wD * d_.w;         \
            dst[ms] = v0; dst[ms + 1] = v1; dst[ms + 2] = v2; dst[ms + 3] = v3; \
            dstmax = fmaxf(dstmax, fmaxf(fmaxf(v0, v1), fmaxf(v2, v3)));      \
        }                                                                     \
    }

template <int HS>
__global__ __launch_bounds__(256, 2) void attnf_kernel(const float* __restrict__ L,
                                                       const float* __restrict__ sbig,
                                                       float* __restrict__ pM,
                                                       float* __restrict__ pSn,
                                                       float* __restrict__ pSw) {
    constexpr int NS = HS * HS;
    constexpr float f = (float)(HS - 1) / 63.0f;
    __shared__ __align__(16) float sl[512];
    int tid = threadIdx.x;
    int b = blockIdx.z;
    int oy0 = blockIdx.y * 8;
    int n = blockIdx.x * 256 + tid;
    {
        const float* sp = sbig + b * 4096 + oy0 * 64;
        sl[tid] = sp[tid];
        sl[tid + 256] = sp[tid + 256];
    }
    __syncthreads();
    int noy = n >> 6, nox = n & 63;
    float cyq = noy * f, cxq = nox * f;
    int iyq = min((int)cyq, HS - 2), ixq = min((int)cxq, HS - 2);
    float wyq = cyq - iyq, wxq = cxq - ixq;
    float wA = (1.f - wyq) * (1.f - wxq), wB = (1.f - wyq) * wxq;
    float wC = wyq * (1.f - wxq), wD = wyq * wxq;
    const float* pA = L + ((size_t)b * NS + iyq * HS + ixq) * NS;
    const float* pB = pA + NS;
    const float* pC = pA + (size_t)HS * NS;
    const float* pD = pC + NS;
    float rA[HS], rB[HS], Lr[HS];
    float rmA = -1e30f, rmB = -1e30f;
    int iyA = -1000;
    float M = -1e30f, Sn = 0.f, Sw = 0.f;
    for (int j = 0; j < 8; ++j) {
        int oy = oy0 + j;
        float cy = oy * f;
        int iy0 = min((int)cy, HS - 2);
        float wy = cy - (float)iy0;
        if (iy0 == iyA + 1) {
#pragma unroll
            for (int ms = 0; ms < HS; ++ms) rA[ms] = rB[ms];
            rmA = rmB;
            CROW(rB, rmB, iy0 + 1)
            iyA = iy0;
        } else if (iy0 != iyA) {
            CROW(rA, rmA, iy0)
            CROW(rB, rmB, iy0 + 1)
            iyA = iy0;
        }
        float Mn = fmaxf(M, fmaxf(rmA, rmB));
        float sc = __expf(M - Mn);
        Sn *= sc; Sw *= sc; M = Mn;
#pragma unroll
        for (int ms = 0; ms < HS; ++ms) Lr[ms] = rA[ms] + wy * (rB[ms] - rA[ms]);
#pragma unroll
        for (int ox4 = 0; ox4 < 64; ox4 += 4) {
            float4 sv = *(const float4*)&sl[j * 64 + ox4];
            float svv[4] = {sv.x, sv.y, sv.z, sv.w};
#pragma unroll
            for (int s4 = 0; s4 < 4; ++s4) {
                int ox = ox4 + s4;
                float cx = ox * f;
                int ix0 = min((int)cx, HS - 2);
                float wx = cx - (float)ix0;
                float v = Lr[ix0] + wx * (Lr[ix0 + 1] - Lr[ix0]);
                float e = __expf(v - M);
                Sn += e;
                Sw += e * svv[s4];
            }
        }
    }
    int pidx = (b * 8 + blockIdx.y) * 4096 + n;
    pM[pidx] = M; pSn[pidx] = Sn; pSw[pidx] = Sw;
}

// --------------------------- scale2 flash attention ------------------------
// LDS-staged k-tile + s-tile (broadcast ds_read_b128), NB=4, 512 blocks.
template <int D, int NB>
__global__ __launch_bounds__(256, 2) void attn2_kernel(const float* __restrict__ base,
                                                       float* __restrict__ pM,
                                                       float* __restrict__ pSn,
                                                       float* __restrict__ pSw) {
    __shared__ __align__(16) float kl[D * 128];
    __shared__ __align__(16) float sl[128];
    int tid = threadIdx.x;
    int b = blockIdx.z, chunk = blockIdx.y;
    int n0 = blockIdx.x * (256 * NB) + tid;
    const float* bb = base + (size_t)b * 65 * 4096;
    float qv[NB][D];
#pragma unroll
    for (int i = 0; i < NB; ++i)
#pragma unroll
        for (int dd = 0; dd < D; ++dd)
            qv[i][dd] = bb[(size_t)dd * 4096 + n0 + i * 256];
    int m0 = chunk * 128;
    for (int fi = tid; fi < D * 32; fi += 256) {
        int dd = fi >> 5;
        int mm = (fi & 31) * 4;
        *(float4*)&kl[dd * 128 + mm] = *(const float4*)&bb[(size_t)(D + dd) * 4096 + m0 + mm];
    }
    if (tid < 32)
        *(float4*)&sl[tid * 4] = *(const float4*)&bb[(size_t)(2 * D) * 4096 + m0 + tid * 4];
    __syncthreads();
    float M[NB], Sn[NB], Sw[NB];
#pragma unroll
    for (int i = 0; i < NB; ++i) { M[i] = -1e30f; Sn[i] = 0.f; Sw[i] = 0.f; }
    for (int mm = 0; mm < 128; mm += 4) {
        float l[NB][4];
#pragma unroll
        for (int i = 0; i < NB; ++i) { l[i][0] = 0.f; l[i][1] = 0.f; l[i][2] = 0.f; l[i][3] = 0.f; }
#pragma unroll
        for (int dd = 0; dd < D; ++dd) {
            float4 kv = *(const float4*)&kl[dd * 128 + mm];
#pragma unroll
            for (int i = 0; i < NB; ++i) {
                float qq = qv[i][dd];
                l[i][0] += qq * kv.x; l[i][1] += qq * kv.y;
                l[i][2] += qq * kv.z; l[i][3] += qq * kv.w;
            }
        }
        float4 sv = *(const float4*)&sl[mm];
#pragma unroll
        for (int i = 0; i < NB; ++i) {
            float lm = fmaxf(fmaxf(l[i][0], l[i][1]), fmaxf(l[i][2], l[i][3]));
            float Mn = fmaxf(M[i], lm);
            float sc = __expf(M[i] - Mn);
            float e0 = __expf(l[i][0] - Mn), e1 = __expf(l[i][1] - Mn);
            float e2 = __expf(l[i][2] - Mn), e3 = __expf(l[i][3] - Mn);
            Sn[i] = Sn[i] * sc + e0 + e1 + e2 + e3;
            Sw[i] = Sw[i] * sc + e0 * sv.x + e1 * sv.y + e2 * sv.z + e3 * sv.w;
            M[i] = Mn;
        }
    }
#pragma unroll
    for (int i = 0; i < NB; ++i) {
        int pidx = (b * 32 + chunk) * 4096 + n0 + i * 256;
        pM[pidx] = M[i]; pSn[pidx] = Sn[i]; pSw[pidx] = Sw[i];
    }
}

// --------------------------- combine + final fusion ------------------------
__global__ __launch_bounds__(256) void final_kernel(const float* __restrict__ ws,
                                                    const float* __restrict__ ba0,
                                                    const float* __restrict__ ba1,
                                                    const float* __restrict__ ba2,
                                                    const float* __restrict__ b1,
                                                    const float* __restrict__ w2,
                                                    const float* __restrict__ b2,
                                                    float* __restrict__ out) {
    __shared__ float lb1[32], lw2[32];
    int tid = threadIdx.x;
    if (tid < 32) { lb1[tid] = b1[tid]; lw2[tid] = w2[tid]; }
    __syncthreads();
    int b = blockIdx.y;
    int n = blockIdx.x * 256 + tid;
    const float* pMs[3]  = {ws + OFF_PM0,  ws + OFF_PM1,  ws + OFF_PM2};
    const float* pSns[3] = {ws + OFF_PSN0, ws + OFF_PSN1, ws + OFF_PSN2};
    const float* pSws[3] = {ws + OFF_PSW0, ws + OFF_PSW1, ws + OFF_PSW2};
    const int ncs[3] = {8, 8, 32};
    float a[3];
#pragma unroll
    for (int s = 0; s < 3; ++s) {
        int nc = ncs[s];
        float Mx = -1e30f;
        for (int ch = 0; ch < nc; ++ch)
            Mx = fmaxf(Mx, pMs[s][(b * nc + ch) * 4096 + n]);
        float Sn = 0.f, Sw = 0.f;
        for (int ch = 0; ch < nc; ++ch) {
            int pi = (b * nc + ch) * 4096 + n;
            float sc = __expf(pMs[s][pi] - Mx);
            Sn += pSns[s][pi] * sc;
            Sw += pSws[s][pi] * sc;
        }
        float bav = (s == 0) ? ba0[0] : (s == 1) ? ba1[0] : ba2[0];
        a[s] = Sw / Sn + bav;
    }
    float prod = a[0] * a[1] * a[2];
    int oy = n >> 6, ox = n & 63;
    float f0 = 15.0f / 63.0f;
    float cy0 = oy * f0, cx0 = ox * f0;
    int iy0 = min((int)cy0, 14), ix0 = min((int)cx0, 14);
    float wy0 = cy0 - iy0, wx0 = cx0 - ix0;
    float f1 = 31.0f / 63.0f;
    float cy1 = oy * f1, cx1 = ox * f1;
    int iy1 = min((int)cy1, 30), ix1 = min((int)cx1, 30);
    float wy1 = cy1 - iy1, wx1 = cx1 - ix1;
    const float* g0b = ws + OFF_PROJ0 + (b * 161 + 129) * 256;
    const float* g1b = ws + OFF_PROJ1 + (b * 97 + 65) * 1024;
    const float* g2b = ws + OFF_PROJ2 + (b * 65 + 33) * 4096;
    float outv = 0.f;
    for (int j = 0; j < 32; ++j) {
        const float* p0 = g0b + j * 256;
        float v0 = (1.f - wy0) * ((1.f - wx0) * p0[iy0 * 16 + ix0] + wx0 * p0[iy0 * 16 + ix0 + 1]) +
                   wy0 * ((1.f - wx0) * p0[(iy0 + 1) * 16 + ix0] + wx0 * p0[(iy0 + 1) * 16 + ix0 + 1]);
        const float* p1 = g1b + j * 1024;
        float v1 = (1.f - wy1) * ((1.f - wx1) * p1[iy1 * 32 + ix1] + wx1 * p1[iy1 * 32 + ix1 + 1]) +
                   wy1 * ((1.f - wx1) * p1[(iy1 + 1) * 32 + ix1] + wx1 * p1[(iy1 + 1) * 32 + ix1 + 1]);
        float g = g2b[j * 4096 + n] + v0 + v1;
        float h = fmaxf(prod * g + lb1[j], 0.f);
        outv += lw2[j] * h;
    }
    out[b * 4096 + n] = outv + b2[0];
}

// ---------------------------------------------------------------------------
extern "C" void kernel_launch(void* const* d_in, const int* in_sizes, int n_in,
                              void* d_out, int out_size, void* d_ws, size_t ws_size,
                              hipStream_t stream) {
    const float* x3 = (const float*)d_in[0];
    const float* x2 = (const float*)d_in[1];
    const float* x1 = (const float*)d_in[2];
    const float* W[24];
    for (int i = 0; i < 24; ++i) W[i] = (const float*)d_in[3 + i];
    const float* w1 = (const float*)d_in[27];
    const float* b1 = (const float*)d_in[28];
    const float* w2 = (const float*)d_in[29];
    const float* b2 = (const float*)d_in[30];
    float* ws = (float*)d_ws;
    float* out = (float*)d_out;

    PrepArgs pa;
    pa.wq0 = W[0];  pa.bq0 = W[1];  pa.wk0 = W[2];  pa.bk0 = W[3];
    pa.wv0 = W[4];  pa.bv0 = W[5];  pa.wa0 = W[6];
    pa.wq1 = W[8];  pa.bq1 = W[9];  pa.wk1 = W[10]; pa.bk1 = W[11];
    pa.wv1 = W[12]; pa.bv1 = W[13]; pa.wa1 = W[14];
    pa.wq2 = W[16]; pa.bq2 = W[17]; pa.wk2 = W[18]; pa.bk2 = W[19];
    pa.wv2 = W[20]; pa.bv2 = W[21]; pa.wa2 = W[22];
    pa.w1 = w1; pa.ws = ws;
    prep_kernel<<<337, 256, 0, stream>>>(pa);

    ProjArgs ja; ja.x0 = x1; ja.x1 = x2; ja.x2 = x3; ja.ws = ws;
    proj_kernel<<<868, 256, 0, stream>>>(ja);

    upsample_s_kernel<<<128, 256, 0, stream>>>(ws);

    // native logit tables (scales 0/1)
    lnat_kernel<64, 256><<<dim3(1, 8, BB), 256, 0, stream>>>(
        ws + OFF_PROJ0, 161, ws + OFF_LN0);
    lnat_kernel<32, 1024><<<dim3(4, 32, BB), 256, 0, stream>>>(
        ws + OFF_PROJ1, 97, ws + OFF_LN1);

    // fused bilerp attention
    attnf_kernel<16><<<dim3(16, 8, BB), 256, 0, stream>>>(
        ws + OFF_LN0, ws + OFF_SBIG0, ws + OFF_PM0, ws + OFF_PSN0, ws + OFF_PSW0);
    attnf_kernel<32><<<dim3(16, 8, BB), 256, 0, stream>>>(
        ws + OFF_LN1, ws + OFF_SBIG1, ws + OFF_PM1, ws + OFF_PSN1, ws + OFF_PSW1);

    // scale2 flash attention
    attn2_kernel<16, 4><<<dim3(4, 32, BB), 256, 0, stream>>>(
        ws + OFF_PROJ2, ws + OFF_PM2, ws + OFF_PSN2, ws + OFF_PSW2);

    final_kernel<<<dim3(16, BB), 256, 0, stream>>>(ws, W[7], W[15], W[23],
                                                   b1, w2, b2, out);
}

// Round 7
// 353.801 us; speedup vs baseline: 1.8978x; 1.0406x over previous
//
#include <hip/hip_runtime.h>

// ---------------------------------------------------------------------------
// MultiScaleFeatureFusion — R7 (= R6 with proj LDS-reduce overflow fixed).
//   scale0: x1 [4,512,16,16]  d=64 C=512 hs=16 Ns=256
//   scale1: x2 [4,256,32,32]  d=32 C=256 hs=32 Ns=1024
//   scale2: x3 [4,128,64,64]  d=16 C=128 hs=64 Ns=4096
// No-max softmax (logits bounded; scale cancels in Sw/Sn) -> additive
// partials everywhere. prep -> proj (m4-vec + c-strips) -> upsample s ->
// lnat (coalesced, thread=ms) -> attnf (per-noy-row blocks, cooperative
// q-bilerped R rows in LDS) -> attn2 (1024 blocks) -> combine -> final.
// ---------------------------------------------------------------------------

#define BB 4

static constexpr int OFF_WP0 = 0;                        // 161*512
static constexpr int OFF_WP1 = OFF_WP0 + 161 * 512;
static constexpr int OFF_WP2 = OFF_WP1 + 97 * 256;
static constexpr int OFF_B0  = OFF_WP2 + 65 * 128;
static constexpr int OFF_B1  = OFF_B0 + 192;
static constexpr int OFF_B2  = OFF_B1 + 128;
static constexpr int OFF_PROJ0 = OFF_B2 + 96;
static constexpr int OFF_PROJ1 = OFF_PROJ0 + BB * 161 * 256;
static constexpr int OFF_PROJ2 = OFF_PROJ1 + BB * 97 * 1024;
static constexpr int OFF_SBIG0 = OFF_PROJ2 + BB * 65 * 4096;   // [b][4096]
static constexpr int OFF_SBIG1 = OFF_SBIG0 + BB * 4096;        // [b][4096]
static constexpr int OFF_LN0   = OFF_SBIG1 + BB * 4096;        // [b][256][256]
static constexpr int OFF_LN1   = OFF_LN0 + BB * 256 * 256;     // [b][1024][1024]
static constexpr int PS01 = BB * 8 * 4096;
static constexpr int PS2  = BB * 64 * 4096;
static constexpr int OFF_PSN0 = OFF_LN1 + BB * 1024 * 1024;
static constexpr int OFF_PSW0 = OFF_PSN0 + PS01;
static constexpr int OFF_PSN1 = OFF_PSW0 + PS01;
static constexpr int OFF_PSW1 = OFF_PSN1 + PS01;
static constexpr int OFF_PSN2 = OFF_PSW1 + PS01;
static constexpr int OFF_PSW2 = OFF_PSN2 + PS2;
static constexpr int OFF_A    = OFF_PSW2 + PS2;                // 3*B*4096

// --------------------------- prep: pack + u --------------------------------
struct PrepArgs {
    const float *wq0, *bq0, *wk0, *bk0, *wv0, *bv0, *wa0;
    const float *wq1, *bq1, *wk1, *bk1, *wv1, *bv1, *wa1;
    const float *wq2, *bq2, *wk2, *bk2, *wv2, *bv2, *wa2;
    const float *w1;
    float *ws;
};

__global__ void prep_kernel(PrepArgs A) {
    __shared__ float red[256];
    int idx = blockIdx.x, tid = threadIdx.x;
    if (idx < 323) {
        int r, C, d, w1off;
        const float *wq, *bq, *wk, *bk;
        float *wp, *bias;
        if (idx < 161) {
            r = idx; C = 512; d = 64; w1off = 384;
            wq = A.wq0; bq = A.bq0; wk = A.wk0; bk = A.bk0;
            wp = A.ws + OFF_WP0; bias = A.ws + OFF_B0;
        } else if (idx < 258) {
            r = idx - 161; C = 256; d = 32; w1off = 128;
            wq = A.wq1; bq = A.bq1; wk = A.wk1; bk = A.bk1;
            wp = A.ws + OFF_WP1; bias = A.ws + OFF_B1;
        } else {
            r = idx - 258; C = 128; d = 16; w1off = 0;
            wq = A.wq2; bq = A.bq2; wk = A.wk2; bk = A.bk2;
            wp = A.ws + OFF_WP2; bias = A.ws + OFF_B2;
        }
        float* dst = wp + r * C;
        if (r < d) {
            for (int c = tid; c < C; c += 256) dst[c] = wq[r * C + c];
            if (tid == 0) bias[r] = bq[r];
        } else if (r < 2 * d) {
            int rr = r - d;
            for (int c = tid; c < C; c += 256) dst[c] = wk[rr * C + c];
            if (tid == 0) bias[r] = bk[rr];
        } else if (r > 2 * d) {
            int j = r - (2 * d + 1);
            for (int c = tid; c < C; c += 256) dst[c] = A.w1[j * 896 + w1off + c];
            if (tid == 0) bias[r] = 0.f;
        }
    } else {
        int ub = idx - 323;
        int lb, C;
        const float *wv, *wa, *bv;
        float *urow, *ubias;
        if (ub < 8) {
            lb = ub; C = 512; wv = A.wv0; wa = A.wa0; bv = A.bv0;
            urow = A.ws + OFF_WP0 + 128 * 512; ubias = A.ws + OFF_B0 + 128;
        } else if (ub < 12) {
            lb = ub - 8; C = 256; wv = A.wv1; wa = A.wa1; bv = A.bv1;
            urow = A.ws + OFF_WP1 + 64 * 256; ubias = A.ws + OFF_B1 + 64;
        } else {
            lb = ub - 12; C = 128; wv = A.wv2; wa = A.wa2; bv = A.bv2;
            urow = A.ws + OFF_WP2 + 32 * 128; ubias = A.ws + OFF_B2 + 32;
        }
        int lci = tid & 63, strip = tid >> 6;
        int ci = lb * 64 + lci;
        float acc = 0.f;
        for (int co = strip; co < C; co += 4) acc += wa[co] * wv[co * C + ci];
        red[tid] = acc;
        __syncthreads();
        if (strip == 0)
            urow[ci] = red[lci] + red[lci + 64] + red[lci + 128] + red[lci + 192];
        if (lb == 0) {
            __syncthreads();
            float bacc = 0.f;
            for (int co = tid; co < C; co += 256) bacc += wa[co] * bv[co];
            red[tid] = bacc;
            __syncthreads();
            for (int off = 128; off > 0; off >>= 1) {
                if (tid < off) red[tid] += red[tid + off];
                __syncthreads();
            }
            if (tid == 0) *ubias = red[0];
        }
    }
}

// --------------------------- proj: all scales ------------------------------
// 256 thr = 64 m-lanes (x4 m via float4) x 4 c-strips; LDS reduce of strips.
struct ProjArgs { const float *x0, *x1, *x2; float* ws; };

__global__ __launch_bounds__(256) void proj_kernel(ProjArgs A) {
    __shared__ __align__(16) float Wl[512 * 8];   // [c][rr]
    __shared__ float bl[8];
    __shared__ float red[8192];                   // [(r*4+j)*4 + strip][lane]  (8*4*4*64)
    int idx = blockIdx.x, tid = threadIdx.x;
    const float *x, *wp, *bias;
    float* out;
    int C, Ns, R, nx, local;
    if (idx < 84) {
        local = idx; x = A.x0; wp = A.ws + OFF_WP0; bias = A.ws + OFF_B0;
        out = A.ws + OFF_PROJ0; C = 512; Ns = 256; R = 161; nx = 1;
    } else if (idx < 292) {
        local = idx - 84; x = A.x1; wp = A.ws + OFF_WP1; bias = A.ws + OFF_B1;
        out = A.ws + OFF_PROJ1; C = 256; Ns = 1024; R = 97; nx = 4;
    } else {
        local = idx - 292; x = A.x2; wp = A.ws + OFF_WP2; bias = A.ws + OFF_B2;
        out = A.ws + OFF_PROJ2; C = 128; Ns = 4096; R = 65; nx = 16;
    }
    int ny = (R + 7) >> 3;
    int pb = nx * ny;
    int b = local / pb;
    int rem = local - b * pb;
    int by = rem / nx;
    int bx = rem - by * nx;
    int r0 = by * 8;
    int nr = min(8, R - r0);
    for (int i = tid; i < C * 8; i += 256) {
        int rr = i & 7, c = i >> 3;
        Wl[i] = (rr < nr) ? wp[(r0 + rr) * C + c] : 0.f;
    }
    if (tid < nr) bl[tid] = bias[r0 + tid];
    __syncthreads();
    int lane = tid & 63, strip = tid >> 6;
    int m0 = bx * 256 + lane * 4;
    const float* xb = x + (size_t)(b * C) * Ns + m0;
    float acc[8][4];
#pragma unroll
    for (int r = 0; r < 8; ++r)
#pragma unroll
        for (int j = 0; j < 4; ++j) acc[r][j] = 0.f;
#pragma unroll 2
    for (int c = strip; c < C; c += 4) {
        float4 xv = *(const float4*)&xb[(size_t)c * Ns];
        float4 w0 = *(const float4*)&Wl[c * 8];
        float4 w1v = *(const float4*)&Wl[c * 8 + 4];
        acc[0][0] += w0.x * xv.x; acc[0][1] += w0.x * xv.y; acc[0][2] += w0.x * xv.z; acc[0][3] += w0.x * xv.w;
        acc[1][0] += w0.y * xv.x; acc[1][1] += w0.y * xv.y; acc[1][2] += w0.y * xv.z; acc[1][3] += w0.y * xv.w;
        acc[2][0] += w0.z * xv.x; acc[2][1] += w0.z * xv.y; acc[2][2] += w0.z * xv.z; acc[2][3] += w0.z * xv.w;
        acc[3][0] += w0.w * xv.x; acc[3][1] += w0.w * xv.y; acc[3][2] += w0.w * xv.z; acc[3][3] += w0.w * xv.w;
        acc[4][0] += w1v.x * xv.x; acc[4][1] += w1v.x * xv.y; acc[4][2] += w1v.x * xv.z; acc[4][3] += w1v.x * xv.w;
        acc[5][0] += w1v.y * xv.x; acc[5][1] += w1v.y * xv.y; acc[5][2] += w1v.y * xv.z; acc[5][3] += w1v.y * xv.w;
        acc[6][0] += w1v.z * xv.x; acc[6][1] += w1v.z * xv.y; acc[6][2] += w1v.z * xv.z; acc[6][3] += w1v.z * xv.w;
        acc[7][0] += w1v.w * xv.x; acc[7][1] += w1v.w * xv.y; acc[7][2] += w1v.w * xv.z; acc[7][3] += w1v.w * xv.w;
    }
#pragma unroll
    for (int r = 0; r < 8; ++r)
#pragma unroll
        for (int j = 0; j < 4; ++j)
            red[((r * 4 + j) * 4 + strip) * 64 + lane] = acc[r][j];
    __syncthreads();
    int g = tid >> 6;  // 2 rows per g
    for (int rr = g * 2; rr < g * 2 + 2; ++rr) {
        if (rr >= nr) continue;
        float v[4];
#pragma unroll
        for (int j = 0; j < 4; ++j) {
            int base = (rr * 4 + j) * 4 * 64 + lane;
            v[j] = red[base] + red[base + 64] + red[base + 128] + red[base + 192] + bl[rr];
        }
        *(float4*)&out[(size_t)(b * R + r0 + rr) * Ns + m0] = make_float4(v[0], v[1], v[2], v[3]);
    }
}

// --------------------------- upsample s rows -------------------------------
__global__ void upsample_s_kernel(float* ws) {
    int idx = blockIdx.x * 256 + threadIdx.x;  // 0..32767
    int seg = idx >> 14;
    int li = idx & 16383;
    int b = li >> 12, n = li & 4095;
    const float* src;
    float* dst;
    int hs;
    if (seg == 0) { src = ws + OFF_PROJ0 + (b * 161 + 128) * 256;  dst = ws + OFF_SBIG0; hs = 16; }
    else          { src = ws + OFF_PROJ1 + (b * 97 + 64) * 1024;   dst = ws + OFF_SBIG1; hs = 32; }
    int oy = n >> 6, ox = n & 63;
    float f = (float)(hs - 1) / 63.0f;
    float cy = oy * f, cx = ox * f;
    int iy0 = min((int)cy, hs - 2);
    int ix0 = min((int)cx, hs - 2);
    float wy = cy - iy0, wx = cx - ix0;
    float v00 = src[iy0 * hs + ix0], v01 = src[iy0 * hs + ix0 + 1];
    float v10 = src[(iy0 + 1) * hs + ix0], v11 = src[(iy0 + 1) * hs + ix0 + 1];
    float t0 = v00 + wx * (v01 - v00), t1 = v10 + wx * (v11 - v10);
    dst[b * 4096 + n] = t0 + wy * (t1 - t0);
}

// --------------------------- native logit table ----------------------------
// L[b][ns][ms] = q_nat[ns].k_nat[ms]; block = 8 ns x NS ms; thread = NM ms.
// Stores coalesced (lanes = consecutive ms).
template <int D, int NS, int NM>
__global__ __launch_bounds__(256) void lnat_kernel(const float* __restrict__ proj, int R,
                                                   float* __restrict__ L) {
    __shared__ __align__(16) float ql[D * 8];
    int tid = threadIdx.x;
    int b = blockIdx.y;
    int ns0 = blockIdx.x * 8;
    const float* pb = proj + (size_t)b * R * NS;
    for (int i = tid; i < D * 8; i += 256)
        ql[i] = pb[(size_t)(i >> 3) * NS + ns0 + (i & 7)];
    __syncthreads();
    float acc[8][NM];
#pragma unroll
    for (int ns = 0; ns < 8; ++ns)
#pragma unroll
        for (int j = 0; j < NM; ++j) acc[ns][j] = 0.f;
    const float* kp = pb + (size_t)D * NS + tid;
    for (int dd = 0; dd < D; ++dd) {
        float kv[NM];
#pragma unroll
        for (int j = 0; j < NM; ++j) kv[j] = kp[(size_t)dd * NS + j * 256];
        float4 qa = *(const float4*)&ql[dd * 8];
        float4 qb = *(const float4*)&ql[dd * 8 + 4];
        float qv[8] = {qa.x, qa.y, qa.z, qa.w, qb.x, qb.y, qb.z, qb.w};
#pragma unroll
        for (int ns = 0; ns < 8; ++ns)
#pragma unroll
            for (int j = 0; j < NM; ++j) acc[ns][j] += qv[ns] * kv[j];
    }
#pragma unroll
    for (int ns = 0; ns < 8; ++ns)
#pragma unroll
        for (int j = 0; j < NM; ++j)
            L[((size_t)b * NS + ns0 + ns) * NS + tid + j * 256] = acc[ns][j];
}

// --------------------------- fused attention (scales 0/1) ------------------
// Block = (oyc m-row chunk of 8, noy output row, b). Threads: 64 nox x 4
// strips (2 oy each). Phase 1: cooperatively build R[iy][ms][nox] =
// q-bilerp of L (global reads are wave-uniform broadcasts; LDS writes/reads
// lane-consecutive). Phase 2: y-lerp rows, unrolled ox-loop, exp-accumulate
// (no max needed: logits bounded, scale cancels in Sw/Sn).
template <int HS, int NIY>
__global__ __launch_bounds__(256, 2) void attnf_kernel(const float* __restrict__ L,
                                                       const float* __restrict__ sbig,
                                                       float* __restrict__ pSn,
                                                       float* __restrict__ pSw) {
    constexpr int NS = HS * HS;
    constexpr float f = (float)(HS - 1) / 63.0f;
    __shared__ float Rl[NIY * HS * 64];
    __shared__ __align__(16) float sl[512];
    __shared__ float redn[256], redw[256];
    int tid = threadIdx.x;
    int oyc = blockIdx.x, noy = blockIdx.y, b = blockIdx.z;
    float cyq = noy * f;
    int iyq = min((int)cyq, HS - 2);
    float wyq = cyq - (float)iyq;
    int iyLo = (int)(oyc * 8 * f);
    const float* Lb = L + (size_t)b * NS * NS;
    {
        const float* sp = sbig + b * 4096 + oyc * 8 * 64;
        sl[tid] = sp[tid];
        sl[tid + 256] = sp[tid + 256];
    }
    // phase 1: R build
    constexpr int MS4 = HS / 4;
    constexpr int NT = 64 * MS4 * NIY;
#pragma unroll
    for (int t = tid; t < NT; t += 256) {
        int nox = t & 63;
        int rest = t >> 6;
        int ms4 = rest % MS4;
        int iyr = rest / MS4;
        float cx = nox * f;
        int ixq = min((int)cx, HS - 2);
        float wx = cx - (float)ixq;
        float w00 = (1.f - wyq) * (1.f - wx), w01 = (1.f - wyq) * wx;
        float w10 = wyq * (1.f - wx), w11 = wyq * wx;
        int iy = min(iyLo + iyr, HS - 1);
        const float* base = Lb + (size_t)(iyq * HS + ixq) * NS + iy * HS + ms4 * 4;
        float4 a = *(const float4*)base;
        float4 bq = *(const float4*)(base + NS);
        float4 c = *(const float4*)(base + (size_t)HS * NS);
        float4 d = *(const float4*)(base + (size_t)HS * NS + NS);
        int ro = (iyr * HS + ms4 * 4) * 64 + nox;
        Rl[ro]       = w00 * a.x + w01 * bq.x + w10 * c.x + w11 * d.x;
        Rl[ro + 64]  = w00 * a.y + w01 * bq.y + w10 * c.y + w11 * d.y;
        Rl[ro + 128] = w00 * a.z + w01 * bq.z + w10 * c.z + w11 * d.z;
        Rl[ro + 192] = w00 * a.w + w01 * bq.w + w10 * c.w + w11 * d.w;
    }
    __syncthreads();
    // phase 2
    int nox = tid & 63, strip = tid >> 6;
    float Sn = 0.f, Sw = 0.f;
#pragma unroll
    for (int k = 0; k < 2; ++k) {
        int oy = oyc * 8 + strip * 2 + k;
        float cy = oy * f;
        int iy0 = min((int)cy, HS - 2);
        float wy = cy - (float)iy0;
        int iyr = iy0 - iyLo;
        float Lr[HS];
#pragma unroll
        for (int ms = 0; ms < HS; ++ms) {
            float r0 = Rl[(iyr * HS + ms) * 64 + nox];
            float r1 = Rl[((iyr + 1) * HS + ms) * 64 + nox];
            Lr[ms] = r0 + wy * (r1 - r0);
        }
        int so = (strip * 2 + k) * 64;
#pragma unroll
        for (int ox = 0; ox < 64; ++ox) {
            float cx = ox * f;
            int ix0 = min((int)cx, HS - 2);
            float wx = cx - (float)ix0;
            float v = Lr[ix0] + wx * (Lr[ix0 + 1] - Lr[ix0]);
            float e = __expf(v);
            Sn += e;
            Sw += e * sl[so + ox];
        }
    }
    redn[strip * 64 + nox] = Sn;
    redw[strip * 64 + nox] = Sw;
    __syncthreads();
    if (strip == 0) {
        float St = redn[nox] + redn[64 + nox] + redn[128 + nox] + redn[192 + nox];
        float Wt = redw[nox] + redw[64 + nox] + redw[128 + nox] + redw[192 + nox];
        int pidx = (b * 8 + oyc) * 4096 + noy * 64 + nox;
        pSn[pidx] = St;
        pSw[pidx] = Wt;
    }
}

// --------------------------- scale2 flash attention ------------------------
// 1024 blocks: (4 n-tiles, 64 m-chunks of 64, B). NB=4. No softmax state.
template <int D, int NB>
__global__ __launch_bounds__(256) void attn2_kernel(const float* __restrict__ base,
                                                    float* __restrict__ pSn,
                                                    float* __restrict__ pSw) {
    __shared__ __align__(16) float kl[D * 64];
    __shared__ __align__(16) float sl[64];
    int tid = threadIdx.x;
    int b = blockIdx.z, chunk = blockIdx.y;
    int n0 = blockIdx.x * (256 * NB) + tid;
    const float* bb = base + (size_t)b * 65 * 4096;
    int m0 = chunk * 64;
    {
        int dd = tid >> 4;
        int mm = (tid & 15) * 4;
        *(float4*)&kl[dd * 64 + mm] = *(const float4*)&bb[(size_t)(D + dd) * 4096 + m0 + mm];
        if (tid < 16)
            *(float4*)&sl[tid * 4] = *(const float4*)&bb[(size_t)(2 * D) * 4096 + m0 + tid * 4];
    }
    float qv[NB][D];
#pragma unroll
    for (int i = 0; i < NB; ++i)
#pragma unroll
        for (int dd = 0; dd < D; ++dd)
            qv[i][dd] = bb[(size_t)dd * 4096 + n0 + i * 256];
    __syncthreads();
    float Sn[NB], Sw[NB];
#pragma unroll
    for (int i = 0; i < NB; ++i) { Sn[i] = 0.f; Sw[i] = 0.f; }
    for (int mm = 0; mm < 64; mm += 4) {
        float l[NB][4];
#pragma unroll
        for (int i = 0; i < NB; ++i) { l[i][0] = 0.f; l[i][1] = 0.f; l[i][2] = 0.f; l[i][3] = 0.f; }
#pragma unroll
        for (int dd = 0; dd < D; ++dd) {
            float4 kv = *(const float4*)&kl[dd * 64 + mm];
#pragma unroll
            for (int i = 0; i < NB; ++i) {
                float qq = qv[i][dd];
                l[i][0] += qq * kv.x; l[i][1] += qq * kv.y;
                l[i][2] += qq * kv.z; l[i][3] += qq * kv.w;
            }
        }
        float4 sv = *(const float4*)&sl[mm];
#pragma unroll
        for (int i = 0; i < NB; ++i) {
            float e0 = __expf(l[i][0]), e1 = __expf(l[i][1]);
            float e2 = __expf(l[i][2]), e3 = __expf(l[i][3]);
            Sn[i] += e0 + e1 + e2 + e3;
            Sw[i] += e0 * sv.x + e1 * sv.y + e2 * sv.z + e3 * sv.w;
        }
    }
#pragma unroll
    for (int i = 0; i < NB; ++i) {
        int pidx = (b * 64 + chunk) * 4096 + n0 + i * 256;
        pSn[pidx] = Sn[i]; pSw[pidx] = Sw[i];
    }
}

// --------------------------- combine partials ------------------------------
__global__ void combine_kernel(const float* __restrict__ ws,
                               const float* __restrict__ ba0,
                               const float* __restrict__ ba1,
                               const float* __restrict__ ba2,
                               float* __restrict__ a) {
    int s = blockIdx.y;
    int idx = blockIdx.x * 256 + threadIdx.x;  // b*4096+n
    int b = idx >> 12, n = idx & 4095;
    const float* pSn;
    const float* pSw;
    int nc;
    if (s == 0)      { pSn = ws + OFF_PSN0; pSw = ws + OFF_PSW0; nc = 8; }
    else if (s == 1) { pSn = ws + OFF_PSN1; pSw = ws + OFF_PSW1; nc = 8; }
    else             { pSn = ws + OFF_PSN2; pSw = ws + OFF_PSW2; nc = 64; }
    float Sn = 0.f, Sw = 0.f;
    for (int ch = 0; ch < nc; ++ch) {
        int pi = (b * nc + ch) * 4096 + n;
        Sn += pSn[pi];
        Sw += pSw[pi];
    }
    float bav = (s == 0) ? ba0[0] : (s == 1) ? ba1[0] : ba2[0];
    a[s * (BB * 4096) + idx] = Sw / Sn + bav;
}

// --------------------------- final fusion ----------------------------------
__global__ __launch_bounds__(256) void final_kernel(const float* __restrict__ ws,
                                                    const float* __restrict__ b1,
                                                    const float* __restrict__ w2,
                                                    const float* __restrict__ b2,
                                                    float* __restrict__ out) {
    __shared__ float lb1[32], lw2[32];
    int tid = threadIdx.x;
    if (tid < 32) { lb1[tid] = b1[tid]; lw2[tid] = w2[tid]; }
    __syncthreads();
    int b = blockIdx.y;
    int n = blockIdx.x * 256 + tid;
    const float* a = ws + OFF_A;
    float prod = a[0 * (BB * 4096) + b * 4096 + n] *
                 a[1 * (BB * 4096) + b * 4096 + n] *
                 a[2 * (BB * 4096) + b * 4096 + n];
    int oy = n >> 6, ox = n & 63;
    float f0 = 15.0f / 63.0f;
    float cy0 = oy * f0, cx0 = ox * f0;
    int iy0 = min((int)cy0, 14), ix0 = min((int)cx0, 14);
    float wy0 = cy0 - iy0, wx0 = cx0 - ix0;
    float f1 = 31.0f / 63.0f;
    float cy1 = oy * f1, cx1 = ox * f1;
    int iy1 = min((int)cy1, 30), ix1 = min((int)cx1, 30);
    float wy1 = cy1 - iy1, wx1 = cx1 - ix1;
    const float* g0b = ws + OFF_PROJ0 + (b * 161 + 129) * 256;
    const float* g1b = ws + OFF_PROJ1 + (b * 97 + 65) * 1024;
    const float* g2b = ws + OFF_PROJ2 + (b * 65 + 33) * 4096;
    float outv = 0.f;
#pragma unroll 4
    for (int j = 0; j < 32; ++j) {
        const float* p0 = g0b + j * 256;
        float v0 = (1.f - wy0) * ((1.f - wx0) * p0[iy0 * 16 + ix0] + wx0 * p0[iy0 * 16 + ix0 + 1]) +
                   wy0 * ((1.f - wx0) * p0[(iy0 + 1) * 16 + ix0] + wx0 * p0[(iy0 + 1) * 16 + ix0 + 1]);
        const float* p1 = g1b + j * 1024;
        float v1 = (1.f - wy1) * ((1.f - wx1) * p1[iy1 * 32 + ix1] + wx1 * p1[iy1 * 32 + ix1 + 1]) +
                   wy1 * ((1.f - wx1) * p1[(iy1 + 1) * 32 + ix1] + wx1 * p1[(iy1 + 1) * 32 + ix1 + 1]);
        float g = g2b[j * 4096 + n] + v0 + v1;
        float h = fmaxf(prod * g + lb1[j], 0.f);
        outv += lw2[j] * h;
    }
    out[b * 4096 + n] = outv + b2[0];
}

// ---------------------------------------------------------------------------
extern "C" void kernel_launch(void* const* d_in, const int* in_sizes, int n_in,
                              void* d_out, int out_size, void* d_ws, size_t ws_size,
                              hipStream_t stream) {
    const float* x3 = (const float*)d_in[0];
    const float* x2 = (const float*)d_in[1];
    const float* x1 = (const float*)d_in[2];
    const float* W[24];
    for (int i = 0; i < 24; ++i) W[i] = (const float*)d_in[3 + i];
    const float* w1 = (const float*)d_in[27];
    const float* b1 = (const float*)d_in[28];
    const float* w2 = (const float*)d_in[29];
    const float* b2 = (const float*)d_in[30];
    float* ws = (float*)d_ws;
    float* out = (float*)d_out;

    PrepArgs pa;
    pa.wq0 = W[0];  pa.bq0 = W[1];  pa.wk0 = W[2];  pa.bk0 = W[3];
    pa.wv0 = W[4];  pa.bv0 = W[5];  pa.wa0 = W[6];
    pa.wq1 = W[8];  pa.bq1 = W[9];  pa.wk1 = W[10]; pa.bk1 = W[11];
    pa.wv1 = W[12]; pa.bv1 = W[13]; pa.wa1 = W[14];
    pa.wq2 = W[16]; pa.bq2 = W[17]; pa.wk2 = W[18]; pa.bk2 = W[19];
    pa.wv2 = W[20]; pa.bv2 = W[21]; pa.wa2 = W[22];
    pa.w1 = w1; pa.ws = ws;
    prep_kernel<<<337, 256, 0, stream>>>(pa);

    ProjArgs ja; ja.x0 = x1; ja.x1 = x2; ja.x2 = x3; ja.ws = ws;
    proj_kernel<<<868, 256, 0, stream>>>(ja);

    upsample_s_kernel<<<128, 256, 0, stream>>>(ws);

    // native logit tables
    lnat_kernel<64, 256, 1><<<dim3(32, BB), 256, 0, stream>>>(
        ws + OFF_PROJ0, 161, ws + OFF_LN0);
    lnat_kernel<32, 1024, 4><<<dim3(128, BB), 256, 0, stream>>>(
        ws + OFF_PROJ1, 97, ws + OFF_LN1);

    // fused bilerp attention: grid (oyc=8, noy=64, b)
    attnf_kernel<16, 4><<<dim3(8, 64, BB), 256, 0, stream>>>(
        ws + OFF_LN0, ws + OFF_SBIG0, ws + OFF_PSN0, ws + OFF_PSW0);
    attnf_kernel<32, 6><<<dim3(8, 64, BB), 256, 0, stream>>>(
        ws + OFF_LN1, ws + OFF_SBIG1, ws + OFF_PSN1, ws + OFF_PSW1);

    // scale2 flash attention
    attn2_kernel<16, 4><<<dim3(4, 64, BB), 256, 0, stream>>>(
        ws + OFF_PROJ2, ws + OFF_PSN2, ws + OFF_PSW2);

    combine_kernel<<<dim3(64, 3), 256, 0, stream>>>(ws, W[7], W[15], W[23], ws + OFF_A);

    final_kernel<<<dim3(16, BB), 256, 0, stream>>>(ws, b1, w2, b2, out);
}

// Round 8
// 320.346 us; speedup vs baseline: 2.0960x; 1.1044x over previous
//
#include <hip/hip_runtime.h>

// ---------------------------------------------------------------------------
// MultiScaleFeatureFusion — R8 (= R7 + scale2 attention on MFMA).
//   scale0: x1 [4,512,16,16]  d=64 C=512 hs=16 Ns=256
//   scale1: x2 [4,256,32,32]  d=32 C=256 hs=32 Ns=1024
//   scale2: x3 [4,128,64,64]  d=16 C=128 hs=64 Ns=4096
// Scale2 QK^T runs as exact split-bf16 MFMA (A=[qh|ql], B1=[kh;kh],
// B2=[kl;kl]; 2 chained mfma_f32_16x16x32_bf16 = full fp32-accurate product),
// log2e pre-folded into q, raw v_exp epilogue, shfl_xor col-reduction.
// ---------------------------------------------------------------------------

#define BB 4

typedef __attribute__((ext_vector_type(8))) short short8;
typedef __attribute__((ext_vector_type(4))) float f32x4;

static constexpr int OFF_WP0 = 0;                        // 161*512
static constexpr int OFF_WP1 = OFF_WP0 + 161 * 512;
static constexpr int OFF_WP2 = OFF_WP1 + 97 * 256;
static constexpr int OFF_B0  = OFF_WP2 + 65 * 128;
static constexpr int OFF_B1  = OFF_B0 + 192;
static constexpr int OFF_B2  = OFF_B1 + 128;
static constexpr int OFF_PROJ0 = OFF_B2 + 96;
static constexpr int OFF_PROJ1 = OFF_PROJ0 + BB * 161 * 256;
static constexpr int OFF_PROJ2 = OFF_PROJ1 + BB * 97 * 1024;
static constexpr int OFF_SBIG0 = OFF_PROJ2 + BB * 65 * 4096;   // [b][4096]
static constexpr int OFF_SBIG1 = OFF_SBIG0 + BB * 4096;        // [b][4096]
static constexpr int OFF_LN0   = OFF_SBIG1 + BB * 4096;        // [b][256][256]
static constexpr int OFF_LN1   = OFF_LN0 + BB * 256 * 256;     // [b][1024][1024]
static constexpr int PS01 = BB * 8 * 4096;
static constexpr int PS2  = BB * 64 * 4096;
static constexpr int OFF_PSN0 = OFF_LN1 + BB * 1024 * 1024;
static constexpr int OFF_PSW0 = OFF_PSN0 + PS01;
static constexpr int OFF_PSN1 = OFF_PSW0 + PS01;
static constexpr int OFF_PSW1 = OFF_PSN1 + PS01;
static constexpr int OFF_PSN2 = OFF_PSW1 + PS01;
static constexpr int OFF_PSW2 = OFF_PSN2 + PS2;
static constexpr int OFF_A    = OFF_PSW2 + PS2;                // 3*B*4096
static constexpr int OFF_KP   = OFF_A + 3 * BB * 4096;         // 4*4096*32 ushort = 512K floats

// --------------------------- prep: pack + u --------------------------------
struct PrepArgs {
    const float *wq0, *bq0, *wk0, *bk0, *wv0, *bv0, *wa0;
    const float *wq1, *bq1, *wk1, *bk1, *wv1, *bv1, *wa1;
    const float *wq2, *bq2, *wk2, *bk2, *wv2, *bv2, *wa2;
    const float *w1;
    float *ws;
};

__global__ void prep_kernel(PrepArgs A) {
    __shared__ float red[256];
    int idx = blockIdx.x, tid = threadIdx.x;
    if (idx < 323) {
        int r, C, d, w1off;
        const float *wq, *bq, *wk, *bk;
        float *wp, *bias;
        if (idx < 161) {
            r = idx; C = 512; d = 64; w1off = 384;
            wq = A.wq0; bq = A.bq0; wk = A.wk0; bk = A.bk0;
            wp = A.ws + OFF_WP0; bias = A.ws + OFF_B0;
        } else if (idx < 258) {
            r = idx - 161; C = 256; d = 32; w1off = 128;
            wq = A.wq1; bq = A.bq1; wk = A.wk1; bk = A.bk1;
            wp = A.ws + OFF_WP1; bias = A.ws + OFF_B1;
        } else {
            r = idx - 258; C = 128; d = 16; w1off = 0;
            wq = A.wq2; bq = A.bq2; wk = A.wk2; bk = A.bk2;
            wp = A.ws + OFF_WP2; bias = A.ws + OFF_B2;
        }
        float* dst = wp + r * C;
        if (r < d) {
            for (int c = tid; c < C; c += 256) dst[c] = wq[r * C + c];
            if (tid == 0) bias[r] = bq[r];
        } else if (r < 2 * d) {
            int rr = r - d;
            for (int c = tid; c < C; c += 256) dst[c] = wk[rr * C + c];
            if (tid == 0) bias[r] = bk[rr];
        } else if (r > 2 * d) {
            int j = r - (2 * d + 1);
            for (int c = tid; c < C; c += 256) dst[c] = A.w1[j * 896 + w1off + c];
            if (tid == 0) bias[r] = 0.f;
        }
    } else {
        int ub = idx - 323;
        int lb, C;
        const float *wv, *wa, *bv;
        float *urow, *ubias;
        if (ub < 8) {
            lb = ub; C = 512; wv = A.wv0; wa = A.wa0; bv = A.bv0;
            urow = A.ws + OFF_WP0 + 128 * 512; ubias = A.ws + OFF_B0 + 128;
        } else if (ub < 12) {
            lb = ub - 8; C = 256; wv = A.wv1; wa = A.wa1; bv = A.bv1;
            urow = A.ws + OFF_WP1 + 64 * 256; ubias = A.ws + OFF_B1 + 64;
        } else {
            lb = ub - 12; C = 128; wv = A.wv2; wa = A.wa2; bv = A.bv2;
            urow = A.ws + OFF_WP2 + 32 * 128; ubias = A.ws + OFF_B2 + 32;
        }
        int lci = tid & 63, strip = tid >> 6;
        int ci = lb * 64 + lci;
        float acc = 0.f;
        for (int co = strip; co < C; co += 4) acc += wa[co] * wv[co * C + ci];
        red[tid] = acc;
        __syncthreads();
        if (strip == 0)
            urow[ci] = red[lci] + red[lci + 64] + red[lci + 128] + red[lci + 192];
        if (lb == 0) {
            __syncthreads();
            float bacc = 0.f;
            for (int co = tid; co < C; co += 256) bacc += wa[co] * bv[co];
            red[tid] = bacc;
            __syncthreads();
            for (int off = 128; off > 0; off >>= 1) {
                if (tid < off) red[tid] += red[tid + off];
                __syncthreads();
            }
            if (tid == 0) *ubias = red[0];
        }
    }
}

// --------------------------- proj: all scales ------------------------------
struct ProjArgs { const float *x0, *x1, *x2; float* ws; };

__global__ __launch_bounds__(256) void proj_kernel(ProjArgs A) {
    __shared__ __align__(16) float Wl[512 * 8];   // [c][rr]
    __shared__ float bl[8];
    __shared__ float red[8192];                   // [(r*4+j)*4 + strip][lane]
    int idx = blockIdx.x, tid = threadIdx.x;
    const float *x, *wp, *bias;
    float* out;
    int C, Ns, R, nx, local;
    if (idx < 84) {
        local = idx; x = A.x0; wp = A.ws + OFF_WP0; bias = A.ws + OFF_B0;
        out = A.ws + OFF_PROJ0; C = 512; Ns = 256; R = 161; nx = 1;
    } else if (idx < 292) {
        local = idx - 84; x = A.x1; wp = A.ws + OFF_WP1; bias = A.ws + OFF_B1;
        out = A.ws + OFF_PROJ1; C = 256; Ns = 1024; R = 97; nx = 4;
    } else {
        local = idx - 292; x = A.x2; wp = A.ws + OFF_WP2; bias = A.ws + OFF_B2;
        out = A.ws + OFF_PROJ2; C = 128; Ns = 4096; R = 65; nx = 16;
    }
    int ny = (R + 7) >> 3;
    int pb = nx * ny;
    int b = local / pb;
    int rem = local - b * pb;
    int by = rem / nx;
    int bx = rem - by * nx;
    int r0 = by * 8;
    int nr = min(8, R - r0);
    for (int i = tid; i < C * 8; i += 256) {
        int rr = i & 7, c = i >> 3;
        Wl[i] = (rr < nr) ? wp[(r0 + rr) * C + c] : 0.f;
    }
    if (tid < nr) bl[tid] = bias[r0 + tid];
    __syncthreads();
    int lane = tid & 63, strip = tid >> 6;
    int m0 = bx * 256 + lane * 4;
    const float* xb = x + (size_t)(b * C) * Ns + m0;
    float acc[8][4];
#pragma unroll
    for (int r = 0; r < 8; ++r)
#pragma unroll
        for (int j = 0; j < 4; ++j) acc[r][j] = 0.f;
#pragma unroll 2
    for (int c = strip; c < C; c += 4) {
        float4 xv = *(const float4*)&xb[(size_t)c * Ns];
        float4 w0 = *(const float4*)&Wl[c * 8];
        float4 w1v = *(const float4*)&Wl[c * 8 + 4];
        acc[0][0] += w0.x * xv.x; acc[0][1] += w0.x * xv.y; acc[0][2] += w0.x * xv.z; acc[0][3] += w0.x * xv.w;
        acc[1][0] += w0.y * xv.x; acc[1][1] += w0.y * xv.y; acc[1][2] += w0.y * xv.z; acc[1][3] += w0.y * xv.w;
        acc[2][0] += w0.z * xv.x; acc[2][1] += w0.z * xv.y; acc[2][2] += w0.z * xv.z; acc[2][3] += w0.z * xv.w;
        acc[3][0] += w0.w * xv.x; acc[3][1] += w0.w * xv.y; acc[3][2] += w0.w * xv.z; acc[3][3] += w0.w * xv.w;
        acc[4][0] += w1v.x * xv.x; acc[4][1] += w1v.x * xv.y; acc[4][2] += w1v.x * xv.z; acc[4][3] += w1v.x * xv.w;
        acc[5][0] += w1v.y * xv.x; acc[5][1] += w1v.y * xv.y; acc[5][2] += w1v.y * xv.z; acc[5][3] += w1v.y * xv.w;
        acc[6][0] += w1v.z * xv.x; acc[6][1] += w1v.z * xv.y; acc[6][2] += w1v.z * xv.z; acc[6][3] += w1v.z * xv.w;
        acc[7][0] += w1v.w * xv.x; acc[7][1] += w1v.w * xv.y; acc[7][2] += w1v.w * xv.z; acc[7][3] += w1v.w * xv.w;
    }
#pragma unroll
    for (int r = 0; r < 8; ++r)
#pragma unroll
        for (int j = 0; j < 4; ++j)
            red[((r * 4 + j) * 4 + strip) * 64 + lane] = acc[r][j];
    __syncthreads();
    int g = tid >> 6;  // 2 rows per g
    for (int rr = g * 2; rr < g * 2 + 2; ++rr) {
        if (rr >= nr) continue;
        float v[4];
#pragma unroll
        for (int j = 0; j < 4; ++j) {
            int base = (rr * 4 + j) * 4 * 64 + lane;
            v[j] = red[base] + red[base + 64] + red[base + 128] + red[base + 192] + bl[rr];
        }
        *(float4*)&out[(size_t)(b * R + r0 + rr) * Ns + m0] = make_float4(v[0], v[1], v[2], v[3]);
    }
}

// --------------------------- upsample s rows -------------------------------
__global__ void upsample_s_kernel(float* ws) {
    int idx = blockIdx.x * 256 + threadIdx.x;  // 0..32767
    int seg = idx >> 14;
    int li = idx & 16383;
    int b = li >> 12, n = li & 4095;
    const float* src;
    float* dst;
    int hs;
    if (seg == 0) { src = ws + OFF_PROJ0 + (b * 161 + 128) * 256;  dst = ws + OFF_SBIG0; hs = 16; }
    else          { src = ws + OFF_PROJ1 + (b * 97 + 64) * 1024;   dst = ws + OFF_SBIG1; hs = 32; }
    int oy = n >> 6, ox = n & 63;
    float f = (float)(hs - 1) / 63.0f;
    float cy = oy * f, cx = ox * f;
    int iy0 = min((int)cy, hs - 2);
    int ix0 = min((int)cx, hs - 2);
    float wy = cy - iy0, wx = cx - ix0;
    float v00 = src[iy0 * hs + ix0], v01 = src[iy0 * hs + ix0 + 1];
    float v10 = src[(iy0 + 1) * hs + ix0], v11 = src[(iy0 + 1) * hs + ix0 + 1];
    float t0 = v00 + wx * (v01 - v00), t1 = v10 + wx * (v11 - v10);
    dst[b * 4096 + n] = t0 + wy * (t1 - t0);
}

// --------------------------- k pack (scale2, bf16 hi/lo) -------------------
// kp[b][m][0:16]=hi(k[d][m]), [16:32]=lo residual; 64 B per m.
__global__ void kpack_kernel(const float* __restrict__ ws_base, ushort* __restrict__ kp) {
    int idx = blockIdx.x * 256 + threadIdx.x;  // 0..16383
    int b = idx >> 12, m = idx & 4095;
    const float* kb = ws_base + OFF_PROJ2 + ((size_t)b * 65 + 16) * 4096 + m;
    ushort out[32];
#pragma unroll
    for (int d = 0; d < 16; ++d) {
        float f = kb[(size_t)d * 4096];
        unsigned u = __float_as_uint(f);
        unsigned hi = u >> 16;
        float r = f - __uint_as_float(hi << 16);
        out[d] = (ushort)hi;
        out[16 + d] = (ushort)(__float_as_uint(r) >> 16);
    }
    ushort* dst = kp + (size_t)idx * 32;
#pragma unroll
    for (int i = 0; i < 4; ++i)
        ((uint4*)dst)[i] = ((const uint4*)out)[i];
}

// --------------------------- native logit table ----------------------------
template <int D, int NS, int NM>
__global__ __launch_bounds__(256) void lnat_kernel(const float* __restrict__ proj, int R,
                                                   float* __restrict__ L) {
    __shared__ __align__(16) float ql[D * 8];
    int tid = threadIdx.x;
    int b = blockIdx.y;
    int ns0 = blockIdx.x * 8;
    const float* pb = proj + (size_t)b * R * NS;
    for (int i = tid; i < D * 8; i += 256)
        ql[i] = pb[(size_t)(i >> 3) * NS + ns0 + (i & 7)];
    __syncthreads();
    float acc[8][NM];
#pragma unroll
    for (int ns = 0; ns < 8; ++ns)
#pragma unroll
        for (int j = 0; j < NM; ++j) acc[ns][j] = 0.f;
    const float* kp = pb + (size_t)D * NS + tid;
    for (int dd = 0; dd < D; ++dd) {
        float kv[NM];
#pragma unroll
        for (int j = 0; j < NM; ++j) kv[j] = kp[(size_t)dd * NS + j * 256];
        float4 qa = *(const float4*)&ql[dd * 8];
        float4 qb = *(const float4*)&ql[dd * 8 + 4];
        float qv[8] = {qa.x, qa.y, qa.z, qa.w, qb.x, qb.y, qb.z, qb.w};
#pragma unroll
        for (int ns = 0; ns < 8; ++ns)
#pragma unroll
            for (int j = 0; j < NM; ++j) acc[ns][j] += qv[ns] * kv[j];
    }
#pragma unroll
    for (int ns = 0; ns < 8; ++ns)
#pragma unroll
        for (int j = 0; j < NM; ++j)
            L[((size_t)b * NS + ns0 + ns) * NS + tid + j * 256] = acc[ns][j];
}

// --------------------------- fused attention (scales 0/1) ------------------
template <int HS, int NIY>
__global__ __launch_bounds__(256, 2) void attnf_kernel(const float* __restrict__ L,
                                                       const float* __restrict__ sbig,
                                                       float* __restrict__ pSn,
                                                       float* __restrict__ pSw) {
    constexpr int NS = HS * HS;
    constexpr float f = (float)(HS - 1) / 63.0f;
    __shared__ float Rl[NIY * HS * 64];
    __shared__ __align__(16) float sl[512];
    __shared__ float redn[256], redw[256];
    int tid = threadIdx.x;
    int oyc = blockIdx.x, noy = blockIdx.y, b = blockIdx.z;
    float cyq = noy * f;
    int iyq = min((int)cyq, HS - 2);
    float wyq = cyq - (float)iyq;
    int iyLo = (int)(oyc * 8 * f);
    const float* Lb = L + (size_t)b * NS * NS;
    {
        const float* sp = sbig + b * 4096 + oyc * 8 * 64;
        sl[tid] = sp[tid];
        sl[tid + 256] = sp[tid + 256];
    }
    // phase 1: R build
    constexpr int MS4 = HS / 4;
    constexpr int NT = 64 * MS4 * NIY;
#pragma unroll
    for (int t = tid; t < NT; t += 256) {
        int nox = t & 63;
        int rest = t >> 6;
        int ms4 = rest % MS4;
        int iyr = rest / MS4;
        float cx = nox * f;
        int ixq = min((int)cx, HS - 2);
        float wx = cx - (float)ixq;
        float w00 = (1.f - wyq) * (1.f - wx), w01 = (1.f - wyq) * wx;
        float w10 = wyq * (1.f - wx), w11 = wyq * wx;
        int iy = min(iyLo + iyr, HS - 1);
        const float* base = Lb + (size_t)(iyq * HS + ixq) * NS + iy * HS + ms4 * 4;
        float4 a = *(const float4*)base;
        float4 bq = *(const float4*)(base + NS);
        float4 c = *(const float4*)(base + (size_t)HS * NS);
        float4 d = *(const float4*)(base + (size_t)HS * NS + NS);
        int ro = (iyr * HS + ms4 * 4) * 64 + nox;
        Rl[ro]       = w00 * a.x + w01 * bq.x + w10 * c.x + w11 * d.x;
        Rl[ro + 64]  = w00 * a.y + w01 * bq.y + w10 * c.y + w11 * d.y;
        Rl[ro + 128] = w00 * a.z + w01 * bq.z + w10 * c.z + w11 * d.z;
        Rl[ro + 192] = w00 * a.w + w01 * bq.w + w10 * c.w + w11 * d.w;
    }
    __syncthreads();
    // phase 2
    int nox = tid & 63, strip = tid >> 6;
    float Sn = 0.f, Sw = 0.f;
#pragma unroll
    for (int k = 0; k < 2; ++k) {
        int oy = oyc * 8 + strip * 2 + k;
        float cy = oy * f;
        int iy0 = min((int)cy, HS - 2);
        float wy = cy - (float)iy0;
        int iyr = iy0 - iyLo;
        float Lr[HS];
#pragma unroll
        for (int ms = 0; ms < HS; ++ms) {
            float r0 = Rl[(iyr * HS + ms) * 64 + nox];
            float r1 = Rl[((iyr + 1) * HS + ms) * 64 + nox];
            Lr[ms] = r0 + wy * (r1 - r0);
        }
        int so = (strip * 2 + k) * 64;
#pragma unroll
        for (int ox = 0; ox < 64; ++ox) {
            float cx = ox * f;
            int ix0 = min((int)cx, HS - 2);
            float wx = cx - (float)ix0;
            float v = Lr[ix0] + wx * (Lr[ix0 + 1] - Lr[ix0]);
            float e = __expf(v);
            Sn += e;
            Sw += e * sl[so + ox];
        }
    }
    redn[strip * 64 + nox] = Sn;
    redw[strip * 64 + nox] = Sw;
    __syncthreads();
    if (strip == 0) {
        float St = redn[nox] + redn[64 + nox] + redn[128 + nox] + redn[192 + nox];
        float Wt = redw[nox] + redw[64 + nox] + redw[128 + nox] + redw[192 + nox];
        int pidx = (b * 8 + oyc) * 4096 + noy * 64 + nox;
        pSn[pidx] = St;
        pSw[pidx] = Wt;
    }
}

// --------------------------- scale2 MFMA flash attention -------------------
// Wave = one 16-n tile, m-chunk of 1024. A=[qh|ql] (log2e-folded), B1/B2 from
// kpack. C tile: col=lane&15 (m), row=quad*4+reg (n). shfl_xor col-reduce.
__global__ __launch_bounds__(256) void attn2_mfma_kernel(const float* __restrict__ ws_base,
                                                         const ushort* __restrict__ kp,
                                                         float* __restrict__ pSn,
                                                         float* __restrict__ pSw) {
    int tid = threadIdx.x;
    int b = blockIdx.z, mc = blockIdx.y;
    int wave = tid >> 6, lane = tid & 63;
    int cc = lane & 15, quad = lane >> 4;
    int n0 = (blockIdx.x * 4 + wave) * 16;
    const float* bb = ws_base + OFF_PROJ2 + (size_t)b * 65 * 4096;
    // A fragment: q rows x log2e, bf16 hi/lo split; k-dim = [hi(16)|lo(16)].
    short8 afrag;
    const float* qb = bb + n0 + cc;
    int dbase = (quad & 1) * 8;
#pragma unroll
    for (int j = 0; j < 8; ++j) {
        float f = qb[(size_t)(dbase + j) * 4096] * 1.44269504f;
        unsigned u = __float_as_uint(f);
        unsigned hi = u >> 16;
        float r = f - __uint_as_float(hi << 16);
        unsigned lo = __float_as_uint(r) >> 16;
        afrag[j] = (short)((quad < 2) ? hi : lo);
    }
    const ushort* kpb = kp + (size_t)b * 4096 * 32;
    const float* srow = bb + (size_t)32 * 4096;
    float Sn[4] = {0.f, 0.f, 0.f, 0.f};
    float Sw[4] = {0.f, 0.f, 0.f, 0.f};
    int hoff = (quad & 1) * 8;
    int mbase = mc * 1024;
    for (int mt = 0; mt < 64; ++mt) {
        int m0 = mbase + mt * 16;
        const ushort* kc = kpb + (size_t)(m0 + cc) * 32;
        short8 b1 = *(const short8*)(kc + hoff);        // kh dup
        short8 b2 = *(const short8*)(kc + 16 + hoff);   // kl dup
        float sv = srow[m0 + cc];
        f32x4 c = {0.f, 0.f, 0.f, 0.f};
        c = __builtin_amdgcn_mfma_f32_16x16x32_bf16(afrag, b2, c, 0, 0, 0);
        c = __builtin_amdgcn_mfma_f32_16x16x32_bf16(afrag, b1, c, 0, 0, 0);
#pragma unroll
        for (int r = 0; r < 4; ++r) {
            float e = exp2f(c[r]);
            Sn[r] += e;
            Sw[r] += e * sv;
        }
    }
#pragma unroll
    for (int mask = 1; mask < 16; mask <<= 1) {
#pragma unroll
        for (int r = 0; r < 4; ++r) {
            Sn[r] += __shfl_xor(Sn[r], mask, 64);
            Sw[r] += __shfl_xor(Sw[r], mask, 64);
        }
    }
    if (cc == 0) {
        int n = n0 + quad * 4;
        int pidx = (b * 4 + mc) * 4096 + n;
        *(float4*)&pSn[pidx] = make_float4(Sn[0], Sn[1], Sn[2], Sn[3]);
        *(float4*)&pSw[pidx] = make_float4(Sw[0], Sw[1], Sw[2], Sw[3]);
    }
}

// --------------------------- combine partials ------------------------------
__global__ void combine_kernel(const float* __restrict__ ws,
                               const float* __restrict__ ba0,
                               const float* __restrict__ ba1,
                               const float* __restrict__ ba2,
                               float* __restrict__ a) {
    int s = blockIdx.y;
    int idx = blockIdx.x * 256 + threadIdx.x;  // b*4096+n
    int b = idx >> 12, n = idx & 4095;
    const float* pSn;
    const float* pSw;
    int nc;
    if (s == 0)      { pSn = ws + OFF_PSN0; pSw = ws + OFF_PSW0; nc = 8; }
    else if (s == 1) { pSn = ws + OFF_PSN1; pSw = ws + OFF_PSW1; nc = 8; }
    else             { pSn = ws + OFF_PSN2; pSw = ws + OFF_PSW2; nc = 4; }
    float Sn = 0.f, Sw = 0.f;
    for (int ch = 0; ch < nc; ++ch) {
        int pi = (b * nc + ch) * 4096 + n;
        Sn += pSn[pi];
        Sw += pSw[pi];
    }
    float bav = (s == 0) ? ba0[0] : (s == 1) ? ba1[0] : ba2[0];
    a[s * (BB * 4096) + idx] = Sw / Sn + bav;
}

// --------------------------- final fusion ----------------------------------
__global__ __launch_bounds__(256) void final_kernel(const float* __restrict__ ws,
                                                    const float* __restrict__ b1,
                                                    const float* __restrict__ w2,
                                                    const float* __restrict__ b2,
                                                    float* __restrict__ out) {
    __shared__ float lb1[32], lw2[32];
    int tid = threadIdx.x;
    if (tid < 32) { lb1[tid] = b1[tid]; lw2[tid] = w2[tid]; }
    __syncthreads();
    int b = blockIdx.y;
    int n = blockIdx.x * 256 + tid;
    const float* a = ws + OFF_A;
    float prod = a[0 * (BB * 4096) + b * 4096 + n] *
                 a[1 * (BB * 4096) + b * 4096 + n] *
                 a[2 * (BB * 4096) + b * 4096 + n];
    int oy = n >> 6, ox = n & 63;
    float f0 = 15.0f / 63.0f;
    float cy0 = oy * f0, cx0 = ox * f0;
    int iy0 = min((int)cy0, 14), ix0 = min((int)cx0, 14);
    float wy0 = cy0 - iy0, wx0 = cx0 - ix0;
    float f1 = 31.0f / 63.0f;
    float cy1 = oy * f1, cx1 = ox * f1;
    int iy1 = min((int)cy1, 30), ix1 = min((int)cx1, 30);
    float wy1 = cy1 - iy1, wx1 = cx1 - ix1;
    const float* g0b = ws + OFF_PROJ0 + (b * 161 + 129) * 256;
    const float* g1b = ws + OFF_PROJ1 + (b * 97 + 65) * 1024;
    const float* g2b = ws + OFF_PROJ2 + (b * 65 + 33) * 4096;
    float outv = 0.f;
#pragma unroll 4
    for (int j = 0; j < 32; ++j) {
        const float* p0 = g0b + j * 256;
        float v0 = (1.f - wy0) * ((1.f - wx0) * p0[iy0 * 16 + ix0] + wx0 * p0[iy0 * 16 + ix0 + 1]) +
                   wy0 * ((1.f - wx0) * p0[(iy0 + 1) * 16 + ix0] + wx0 * p0[(iy0 + 1) * 16 + ix0 + 1]);
        const float* p1 = g1b + j * 1024;
        float v1 = (1.f - wy1) * ((1.f - wx1) * p1[iy1 * 32 + ix1] + wx1 * p1[iy1 * 32 + ix1 + 1]) +
                   wy1 * ((1.f - wx1) * p1[(iy1 + 1) * 32 + ix1] + wx1 * p1[(iy1 + 1) * 32 + ix1 + 1]);
        float g = g2b[j * 4096 + n] + v0 + v1;
        float h = fmaxf(prod * g + lb1[j], 0.f);
        outv += lw2[j] * h;
    }
    out[b * 4096 + n] = outv + b2[0];
}

// ---------------------------------------------------------------------------
extern "C" void kernel_launch(void* const* d_in, const int* in_sizes, int n_in,
                              void* d_out, int out_size, void* d_ws, size_t ws_size,
                              hipStream_t stream) {
    const float* x3 = (const float*)d_in[0];
    const float* x2 = (const float*)d_in[1];
    const float* x1 = (const float*)d_in[2];
    const float* W[24];
    for (int i = 0; i < 24; ++i) W[i] = (const float*)d_in[3 + i];
    const float* w1 = (const float*)d_in[27];
    const float* b1 = (const float*)d_in[28];
    const float* w2 = (const float*)d_in[29];
    const float* b2 = (const float*)d_in[30];
    float* ws = (float*)d_ws;
    float* out = (float*)d_out;

    PrepArgs pa;
    pa.wq0 = W[0];  pa.bq0 = W[1];  pa.wk0 = W[2];  pa.bk0 = W[3];
    pa.wv0 = W[4];  pa.bv0 = W[5];  pa.wa0 = W[6];
    pa.wq1 = W[8];  pa.bq1 = W[9];  pa.wk1 = W[10]; pa.bk1 = W[11];
    pa.wv1 = W[12]; pa.bv1 = W[13]; pa.wa1 = W[14];
    pa.wq2 = W[16]; pa.bq2 = W[17]; pa.wk2 = W[18]; pa.bk2 = W[19];
    pa.wv2 = W[20]; pa.bv2 = W[21]; pa.wa2 = W[22];
    pa.w1 = w1; pa.ws = ws;
    prep_kernel<<<337, 256, 0, stream>>>(pa);

    ProjArgs ja; ja.x0 = x1; ja.x1 = x2; ja.x2 = x3; ja.ws = ws;
    proj_kernel<<<868, 256, 0, stream>>>(ja);

    upsample_s_kernel<<<128, 256, 0, stream>>>(ws);
    kpack_kernel<<<64, 256, 0, stream>>>(ws, (ushort*)(ws + OFF_KP));

    // native logit tables
    lnat_kernel<64, 256, 1><<<dim3(32, BB), 256, 0, stream>>>(
        ws + OFF_PROJ0, 161, ws + OFF_LN0);
    lnat_kernel<32, 1024, 4><<<dim3(128, BB), 256, 0, stream>>>(
        ws + OFF_PROJ1, 97, ws + OFF_LN1);

    // fused bilerp attention: grid (oyc=8, noy=64, b)
    attnf_kernel<16, 4><<<dim3(8, 64, BB), 256, 0, stream>>>(
        ws + OFF_LN0, ws + OFF_SBIG0, ws + OFF_PSN0, ws + OFF_PSW0);
    attnf_kernel<32, 6><<<dim3(8, 64, BB), 256, 0, stream>>>(
        ws + OFF_LN1, ws + OFF_SBIG1, ws + OFF_PSN1, ws + OFF_PSW1);

    // scale2 MFMA flash attention: grid (64 n-blocks, 4 m-chunks, B)
    attn2_mfma_kernel<<<dim3(64, 4, BB), 256, 0, stream>>>(
        ws, (const ushort*)(ws + OFF_KP), ws + OFF_PSN2, ws + OFF_PSW2);

    combine_kernel<<<dim3(64, 3), 256, 0, stream>>>(ws, W[7], W[15], W[23], ws + OFF_A);

    final_kernel<<<dim3(16, BB), 256, 0, stream>>>(ws, b1, w2, b2, out);
}

// Round 9
// 278.795 us; speedup vs baseline: 2.4083x; 1.1490x over previous
//
#include <hip/hip_runtime.h>

// ---------------------------------------------------------------------------
// MultiScaleFeatureFusion — R9.
//   scale0: x1 [4,512,16,16]  d=64 C=512 hs=16 Ns=256  R=161
//   scale1: x2 [4,256,32,32]  d=32 C=256 hs=32 Ns=1024 R=97
//   scale2: x3 [4,128,64,64]  d=16 C=128 hs=64 Ns=4096 R=65
// R9: pack kernel eliminated (proj stages weights straight from inputs;
// u-row = sum of 4 co-chunk partials from a parallel u_kernel); proj main
// loop unroll x4; combine folded into final; upsample+kpack merged.
// Scale2 QK^T on exact split-bf16 MFMA (R8). No-max softmax throughout.
// ---------------------------------------------------------------------------

#define BB 4

typedef __attribute__((ext_vector_type(8))) short short8;
typedef __attribute__((ext_vector_type(4))) float f32x4;

static constexpr int OFF_UP0 = 0;                        // [4][512]
static constexpr int OFF_UP1 = OFF_UP0 + 4 * 512;
static constexpr int OFF_UP2 = OFF_UP1 + 4 * 256;
static constexpr int OFF_UB0 = OFF_UP2 + 4 * 128;        // [4] each
static constexpr int OFF_UB1 = OFF_UB0 + 4;
static constexpr int OFF_UB2 = OFF_UB1 + 4;
static constexpr int OFF_PROJ0 = OFF_UB2 + 4;            // 4-float aligned
static constexpr int OFF_PROJ1 = OFF_PROJ0 + BB * 161 * 256;
static constexpr int OFF_PROJ2 = OFF_PROJ1 + BB * 97 * 1024;
static constexpr int OFF_SBIG0 = OFF_PROJ2 + BB * 65 * 4096;   // [b][4096]
static constexpr int OFF_SBIG1 = OFF_SBIG0 + BB * 4096;        // [b][4096]
static constexpr int OFF_LN0   = OFF_SBIG1 + BB * 4096;        // [b][256][256]
static constexpr int OFF_LN1   = OFF_LN0 + BB * 256 * 256;     // [b][1024][1024]
static constexpr int PS01 = BB * 8 * 4096;
static constexpr int PS2  = BB * 4 * 4096;
static constexpr int OFF_PSN0 = OFF_LN1 + BB * 1024 * 1024;
static constexpr int OFF_PSW0 = OFF_PSN0 + PS01;
static constexpr int OFF_PSN1 = OFF_PSW0 + PS01;
static constexpr int OFF_PSW1 = OFF_PSN1 + PS01;
static constexpr int OFF_PSN2 = OFF_PSW1 + PS01;
static constexpr int OFF_PSW2 = OFF_PSN2 + PS2;
static constexpr int OFF_KP   = OFF_PSW2 + PS2;                // 4*4096*32 ushort

// --------------------------- u partials ------------------------------------
// u[ci] = sum_co wa[co]*wv[co][ci], split into 4 co-chunk partials.
// grid 56: s0 8 ci-tiles x4 chunks, s1 4x4, s2 2x4. cit==0 blocks also do
// the bias partial ub[chunk] = sum wa*bv over their co-range.
struct UArgs {
    const float *wv0, *wa0, *bv0;
    const float *wv1, *wa1, *bv1;
    const float *wv2, *wa2, *bv2;
    float* ws;
};

__global__ void u_kernel(UArgs A) {
    __shared__ float red[256];
    int idx = blockIdx.x, tid = threadIdx.x;
    int C, cit, chunk;
    const float *wv, *wa, *bv;
    float *up, *ub;
    if (idx < 32) {
        C = 512; cit = idx >> 2; chunk = idx & 3;
        wv = A.wv0; wa = A.wa0; bv = A.bv0;
        up = A.ws + OFF_UP0; ub = A.ws + OFF_UB0;
    } else if (idx < 48) {
        int i2 = idx - 32;
        C = 256; cit = i2 >> 2; chunk = i2 & 3;
        wv = A.wv1; wa = A.wa1; bv = A.bv1;
        up = A.ws + OFF_UP1; ub = A.ws + OFF_UB1;
    } else {
        int i2 = idx - 48;
        C = 128; cit = i2 >> 2; chunk = i2 & 3;
        wv = A.wv2; wa = A.wa2; bv = A.bv2;
        up = A.ws + OFF_UP2; ub = A.ws + OFF_UB2;
    }
    int lci = tid & 63, sub = tid >> 6;
    int ci = cit * 64 + lci;
    int coBeg = chunk * (C >> 2), coEnd = coBeg + (C >> 2);
    float acc = 0.f;
#pragma unroll 4
    for (int co = coBeg + sub; co < coEnd; co += 4)
        acc += wa[co] * wv[(size_t)co * C + ci];
    red[tid] = acc;
    __syncthreads();
    if (sub == 0)
        up[chunk * C + ci] = red[lci] + red[lci + 64] + red[lci + 128] + red[lci + 192];
    if (cit == 0) {
        __syncthreads();
        float bacc = 0.f;
        for (int co = coBeg + tid; co < coEnd; co += 256) bacc += wa[co] * bv[co];
        red[tid] = bacc;
        __syncthreads();
        for (int off = 128; off > 0; off >>= 1) {
            if (tid < off) red[tid] += red[tid + off];
            __syncthreads();
        }
        if (tid == 0) ub[chunk] = red[0];
    }
}

// --------------------------- proj: all scales ------------------------------
// Stages W rows straight from inputs: [wq(d) | wk(d) | u | w1-slice(32)].
// 256 thr = 64 m-lanes (x4 m via float4) x 4 c-strips; LDS strip-reduce.
struct ProjArgs {
    const float *x0, *x1, *x2;
    const float *wq0, *wk0, *bq0, *bk0;
    const float *wq1, *wk1, *bq1, *bk1;
    const float *wq2, *wk2, *bq2, *bk2;
    const float *w1;
    float* ws;
};

__global__ __launch_bounds__(256) void proj_kernel(ProjArgs A) {
    __shared__ __align__(16) float Wl[512 * 8];   // [c][rr]
    __shared__ float bl[8];
    __shared__ float red[8192];
    int idx = blockIdx.x, tid = threadIdx.x;
    const float *x, *wq, *wk, *bq, *bk, *up, *ub;
    float* out;
    int C, Ns, R, nx, d, w1off, local;
    if (idx < 84) {
        local = idx; x = A.x0; out = A.ws + OFF_PROJ0;
        wq = A.wq0; wk = A.wk0; bq = A.bq0; bk = A.bk0;
        up = A.ws + OFF_UP0; ub = A.ws + OFF_UB0;
        C = 512; Ns = 256; R = 161; nx = 1; d = 64; w1off = 384;
    } else if (idx < 292) {
        local = idx - 84; x = A.x1; out = A.ws + OFF_PROJ1;
        wq = A.wq1; wk = A.wk1; bq = A.bq1; bk = A.bk1;
        up = A.ws + OFF_UP1; ub = A.ws + OFF_UB1;
        C = 256; Ns = 1024; R = 97; nx = 4; d = 32; w1off = 128;
    } else {
        local = idx - 292; x = A.x2; out = A.ws + OFF_PROJ2;
        wq = A.wq2; wk = A.wk2; bq = A.bq2; bk = A.bk2;
        up = A.ws + OFF_UP2; ub = A.ws + OFF_UB2;
        C = 128; Ns = 4096; R = 65; nx = 16; d = 16; w1off = 0;
    }
    int ny = (R + 7) >> 3;
    int pb = nx * ny;
    int b = local / pb;
    int rem = local - b * pb;
    int by = rem / nx;
    int bx = rem - by * nx;
    int r0 = by * 8;
    int nr = min(8, R - r0);
    // stage: wave-grouped rows (2 rr per wave), 32 lanes over c.
    {
        int rr = tid >> 5, cg = tid & 31;
        int gr = r0 + rr;
        if (gr == 2 * d) {
            for (int c = cg; c < C; c += 32)
                Wl[c * 8 + rr] = up[c] + up[C + c] + up[2 * C + c] + up[3 * C + c];
        } else {
            const float* rowsrc;
            if (gr < d) rowsrc = wq + (size_t)gr * C;
            else if (gr < 2 * d) rowsrc = wk + (size_t)(gr - d) * C;
            else if (gr < R) rowsrc = A.w1 + (size_t)(gr - 2 * d - 1) * 896 + w1off;
            else rowsrc = nullptr;
            if (rowsrc) {
                for (int c = cg; c < C; c += 32) Wl[c * 8 + rr] = rowsrc[c];
            } else {
                for (int c = cg; c < C; c += 32) Wl[c * 8 + rr] = 0.f;
            }
        }
        if (tid < 8) {
            int g2 = r0 + tid;
            float bv2;
            if (g2 < d) bv2 = bq[g2];
            else if (g2 < 2 * d) bv2 = bk[g2 - d];
            else if (g2 == 2 * d) bv2 = ub[0] + ub[1] + ub[2] + ub[3];
            else bv2 = 0.f;
            bl[tid] = bv2;
        }
    }
    __syncthreads();
    int lane = tid & 63, strip = tid >> 6;
    int m0 = bx * 256 + lane * 4;
    const float* xb = x + (size_t)(b * C) * Ns + m0;
    float acc[8][4];
#pragma unroll
    for (int r = 0; r < 8; ++r)
#pragma unroll
        for (int j = 0; j < 4; ++j) acc[r][j] = 0.f;
#pragma unroll 4
    for (int c = strip; c < C; c += 4) {
        float4 xv = *(const float4*)&xb[(size_t)c * Ns];
        float4 w0 = *(const float4*)&Wl[c * 8];
        float4 w1v = *(const float4*)&Wl[c * 8 + 4];
        acc[0][0] += w0.x * xv.x; acc[0][1] += w0.x * xv.y; acc[0][2] += w0.x * xv.z; acc[0][3] += w0.x * xv.w;
        acc[1][0] += w0.y * xv.x; acc[1][1] += w0.y * xv.y; acc[1][2] += w0.y * xv.z; acc[1][3] += w0.y * xv.w;
        acc[2][0] += w0.z * xv.x; acc[2][1] += w0.z * xv.y; acc[2][2] += w0.z * xv.z; acc[2][3] += w0.z * xv.w;
        acc[3][0] += w0.w * xv.x; acc[3][1] += w0.w * xv.y; acc[3][2] += w0.w * xv.z; acc[3][3] += w0.w * xv.w;
        acc[4][0] += w1v.x * xv.x; acc[4][1] += w1v.x * xv.y; acc[4][2] += w1v.x * xv.z; acc[4][3] += w1v.x * xv.w;
        acc[5][0] += w1v.y * xv.x; acc[5][1] += w1v.y * xv.y; acc[5][2] += w1v.y * xv.z; acc[5][3] += w1v.y * xv.w;
        acc[6][0] += w1v.z * xv.x; acc[6][1] += w1v.z * xv.y; acc[6][2] += w1v.z * xv.z; acc[6][3] += w1v.z * xv.w;
        acc[7][0] += w1v.w * xv.x; acc[7][1] += w1v.w * xv.y; acc[7][2] += w1v.w * xv.z; acc[7][3] += w1v.w * xv.w;
    }
#pragma unroll
    for (int r = 0; r < 8; ++r)
#pragma unroll
        for (int j = 0; j < 4; ++j)
            red[((r * 4 + j) * 4 + strip) * 64 + lane] = acc[r][j];
    __syncthreads();
    int g = tid >> 6;  // 2 rows per g
    for (int rr = g * 2; rr < g * 2 + 2; ++rr) {
        if (rr >= nr) continue;
        float v[4];
#pragma unroll
        for (int j = 0; j < 4; ++j) {
            int base = (rr * 4 + j) * 4 * 64 + lane;
            v[j] = red[base] + red[base + 64] + red[base + 128] + red[base + 192] + bl[rr];
        }
        *(float4*)&out[(size_t)(b * R + r0 + rr) * Ns + m0] = make_float4(v[0], v[1], v[2], v[3]);
    }
}

// --------------------------- aux: upsample s rows + kpack ------------------
__global__ void aux_kernel(float* ws) {
    int tid = threadIdx.x;
    if (blockIdx.x < 128) {
        int idx = blockIdx.x * 256 + tid;  // 0..32767
        int seg = idx >> 14;
        int li = idx & 16383;
        int b = li >> 12, n = li & 4095;
        const float* src;
        float* dst;
        int hs;
        if (seg == 0) { src = ws + OFF_PROJ0 + (b * 161 + 128) * 256;  dst = ws + OFF_SBIG0; hs = 16; }
        else          { src = ws + OFF_PROJ1 + (b * 97 + 64) * 1024;   dst = ws + OFF_SBIG1; hs = 32; }
        int oy = n >> 6, ox = n & 63;
        float f = (float)(hs - 1) / 63.0f;
        float cy = oy * f, cx = ox * f;
        int iy0 = min((int)cy, hs - 2);
        int ix0 = min((int)cx, hs - 2);
        float wy = cy - iy0, wx = cx - ix0;
        float v00 = src[iy0 * hs + ix0], v01 = src[iy0 * hs + ix0 + 1];
        float v10 = src[(iy0 + 1) * hs + ix0], v11 = src[(iy0 + 1) * hs + ix0 + 1];
        float t0 = v00 + wx * (v01 - v00), t1 = v10 + wx * (v11 - v10);
        dst[b * 4096 + n] = t0 + wy * (t1 - t0);
    } else {
        // kpack: kp[b][m][0:16]=hi(k), [16:32]=lo residual
        int idx = (blockIdx.x - 128) * 256 + tid;  // 0..16383
        int b = idx >> 12, m = idx & 4095;
        const float* kb = ws + OFF_PROJ2 + ((size_t)b * 65 + 16) * 4096 + m;
        ushort* kp = (ushort*)(ws + OFF_KP);
        ushort outv[32];
#pragma unroll
        for (int d = 0; d < 16; ++d) {
            float f = kb[(size_t)d * 4096];
            unsigned u = __float_as_uint(f);
            unsigned hi = u >> 16;
            float r = f - __uint_as_float(hi << 16);
            outv[d] = (ushort)hi;
            outv[16 + d] = (ushort)(__float_as_uint(r) >> 16);
        }
        ushort* dst = kp + (size_t)idx * 32;
#pragma unroll
        for (int i = 0; i < 4; ++i)
            ((uint4*)dst)[i] = ((const uint4*)outv)[i];
    }
}

// --------------------------- native logit table ----------------------------
template <int D, int NS, int NM>
__global__ __launch_bounds__(256) void lnat_kernel(const float* __restrict__ proj, int R,
                                                   float* __restrict__ L) {
    __shared__ __align__(16) float ql[D * 8];
    int tid = threadIdx.x;
    int b = blockIdx.y;
    int ns0 = blockIdx.x * 8;
    const float* pb = proj + (size_t)b * R * NS;
    for (int i = tid; i < D * 8; i += 256)
        ql[i] = pb[(size_t)(i >> 3) * NS + ns0 + (i & 7)];
    __syncthreads();
    float acc[8][NM];
#pragma unroll
    for (int ns = 0; ns < 8; ++ns)
#pragma unroll
        for (int j = 0; j < NM; ++j) acc[ns][j] = 0.f;
    const float* kp = pb + (size_t)D * NS + tid;
    for (int dd = 0; dd < D; ++dd) {
        float kv[NM];
#pragma unroll
        for (int j = 0; j < NM; ++j) kv[j] = kp[(size_t)dd * NS + j * 256];
        float4 qa = *(const float4*)&ql[dd * 8];
        float4 qb = *(const float4*)&ql[dd * 8 + 4];
        float qv[8] = {qa.x, qa.y, qa.z, qa.w, qb.x, qb.y, qb.z, qb.w};
#pragma unroll
        for (int ns = 0; ns < 8; ++ns)
#pragma unroll
            for (int j = 0; j < NM; ++j) acc[ns][j] += qv[ns] * kv[j];
    }
#pragma unroll
    for (int ns = 0; ns < 8; ++ns)
#pragma unroll
        for (int j = 0; j < NM; ++j)
            L[((size_t)b * NS + ns0 + ns) * NS + tid + j * 256] = acc[ns][j];
}

// --------------------------- fused attention (scales 0/1) ------------------
template <int HS, int NIY>
__global__ __launch_bounds__(256, 2) void attnf_kernel(const float* __restrict__ L,
                                                       const float* __restrict__ sbig,
                                                       float* __restrict__ pSn,
                                                       float* __restrict__ pSw) {
    constexpr int NS = HS * HS;
    constexpr float f = (float)(HS - 1) / 63.0f;
    __shared__ float Rl[NIY * HS * 64];
    __shared__ __align__(16) float sl[512];
    __shared__ float redn[256], redw[256];
    int tid = threadIdx.x;
    int oyc = blockIdx.x, noy = blockIdx.y, b = blockIdx.z;
    float cyq = noy * f;
    int iyq = min((int)cyq, HS - 2);
    float wyq = cyq - (float)iyq;
    int iyLo = (int)(oyc * 8 * f);
    const float* Lb = L + (size_t)b * NS * NS;
    {
        const float* sp = sbig + b * 4096 + oyc * 8 * 64;
        sl[tid] = sp[tid];
        sl[tid + 256] = sp[tid + 256];
    }
    // phase 1: R build
    constexpr int MS4 = HS / 4;
    constexpr int NT = 64 * MS4 * NIY;
#pragma unroll
    for (int t = tid; t < NT; t += 256) {
        int nox = t & 63;
        int rest = t >> 6;
        int ms4 = rest % MS4;
        int iyr = rest / MS4;
        float cx = nox * f;
        int ixq = min((int)cx, HS - 2);
        float wx = cx - (float)ixq;
        float w00 = (1.f - wyq) * (1.f - wx), w01 = (1.f - wyq) * wx;
        float w10 = wyq * (1.f - wx), w11 = wyq * wx;
        int iy = min(iyLo + iyr, HS - 1);
        const float* base = Lb + (size_t)(iyq * HS + ixq) * NS + iy * HS + ms4 * 4;
        float4 a = *(const float4*)base;
        float4 bq = *(const float4*)(base + NS);
        float4 c = *(const float4*)(base + (size_t)HS * NS);
        float4 d = *(const float4*)(base + (size_t)HS * NS + NS);
        int ro = (iyr * HS + ms4 * 4) * 64 + nox;
        Rl[ro]       = w00 * a.x + w01 * bq.x + w10 * c.x + w11 * d.x;
        Rl[ro + 64]  = w00 * a.y + w01 * bq.y + w10 * c.y + w11 * d.y;
        Rl[ro + 128] = w00 * a.z + w01 * bq.z + w10 * c.z + w11 * d.z;
        Rl[ro + 192] = w00 * a.w + w01 * bq.w + w10 * c.w + w11 * d.w;
    }
    __syncthreads();
    // phase 2
    int nox = tid & 63, strip = tid >> 6;
    float Sn = 0.f, Sw = 0.f;
#pragma unroll
    for (int k = 0; k < 2; ++k) {
        int oy = oyc * 8 + strip * 2 + k;
        float cy = oy * f;
        int iy0 = min((int)cy, HS - 2);
        float wy = cy - (float)iy0;
        int iyr = iy0 - iyLo;
        float Lr[HS];
#pragma unroll
        for (int ms = 0; ms < HS; ++ms) {
            float r0 = Rl[(iyr * HS + ms) * 64 + nox];
            float r1 = Rl[((iyr + 1) * HS + ms) * 64 + nox];
            Lr[ms] = r0 + wy * (r1 - r0);
        }
        int so = (strip * 2 + k) * 64;
#pragma unroll
        for (int ox = 0; ox < 64; ++ox) {
            float cx = ox * f;
            int ix0 = min((int)cx, HS - 2);
            float wx = cx - (float)ix0;
            float v = Lr[ix0] + wx * (Lr[ix0 + 1] - Lr[ix0]);
            float e = __expf(v);
            Sn += e;
            Sw += e * sl[so + ox];
        }
    }
    redn[strip * 64 + nox] = Sn;
    redw[strip * 64 + nox] = Sw;
    __syncthreads();
    if (strip == 0) {
        float St = redn[nox] + redn[64 + nox] + redn[128 + nox] + redn[192 + nox];
        float Wt = redw[nox] + redw[64 + nox] + redw[128 + nox] + redw[192 + nox];
        int pidx = (b * 8 + oyc) * 4096 + noy * 64 + nox;
        pSn[pidx] = St;
        pSw[pidx] = Wt;
    }
}

// --------------------------- scale2 MFMA flash attention -------------------
__global__ __launch_bounds__(256) void attn2_mfma_kernel(const float* __restrict__ ws_base,
                                                         const ushort* __restrict__ kp,
                                                         float* __restrict__ pSn,
                                                         float* __restrict__ pSw) {
    int tid = threadIdx.x;
    int b = blockIdx.z, mc = blockIdx.y;
    int wave = tid >> 6, lane = tid & 63;
    int cc = lane & 15, quad = lane >> 4;
    int n0 = (blockIdx.x * 4 + wave) * 16;
    const float* bb = ws_base + OFF_PROJ2 + (size_t)b * 65 * 4096;
    short8 afrag;
    const float* qb = bb + n0 + cc;
    int dbase = (quad & 1) * 8;
#pragma unroll
    for (int j = 0; j < 8; ++j) {
        float f = qb[(size_t)(dbase + j) * 4096] * 1.44269504f;
        unsigned u = __float_as_uint(f);
        unsigned hi = u >> 16;
        float r = f - __uint_as_float(hi << 16);
        unsigned lo = __float_as_uint(r) >> 16;
        afrag[j] = (short)((quad < 2) ? hi : lo);
    }
    const ushort* kpb = kp + (size_t)b * 4096 * 32;
    const float* srow = bb + (size_t)32 * 4096;
    float Sn[4] = {0.f, 0.f, 0.f, 0.f};
    float Sw[4] = {0.f, 0.f, 0.f, 0.f};
    int hoff = (quad & 1) * 8;
    int mbase = mc * 1024;
    for (int mt = 0; mt < 64; ++mt) {
        int m0 = mbase + mt * 16;
        const ushort* kc = kpb + (size_t)(m0 + cc) * 32;
        short8 b1 = *(const short8*)(kc + hoff);        // kh dup
        short8 b2 = *(const short8*)(kc + 16 + hoff);   // kl dup
        float sv = srow[m0 + cc];
        f32x4 c = {0.f, 0.f, 0.f, 0.f};
        c = __builtin_amdgcn_mfma_f32_16x16x32_bf16(afrag, b2, c, 0, 0, 0);
        c = __builtin_amdgcn_mfma_f32_16x16x32_bf16(afrag, b1, c, 0, 0, 0);
#pragma unroll
        for (int r = 0; r < 4; ++r) {
            float e = exp2f(c[r]);
            Sn[r] += e;
            Sw[r] += e * sv;
        }
    }
#pragma unroll
    for (int mask = 1; mask < 16; mask <<= 1) {
#pragma unroll
        for (int r = 0; r < 4; ++r) {
            Sn[r] += __shfl_xor(Sn[r], mask, 64);
            Sw[r] += __shfl_xor(Sw[r], mask, 64);
        }
    }
    if (cc == 0) {
        int n = n0 + quad * 4;
        int pidx = (b * 4 + mc) * 4096 + n;
        *(float4*)&pSn[pidx] = make_float4(Sn[0], Sn[1], Sn[2], Sn[3]);
        *(float4*)&pSw[pidx] = make_float4(Sw[0], Sw[1], Sw[2], Sw[3]);
    }
}

// --------------------------- final: combine + fusion -----------------------
__global__ __launch_bounds__(256) void final_kernel(const float* __restrict__ ws,
                                                    const float* __restrict__ ba0,
                                                    const float* __restrict__ ba1,
                                                    const float* __restrict__ ba2,
                                                    const float* __restrict__ b1,
                                                    const float* __restrict__ w2,
                                                    const float* __restrict__ b2,
                                                    float* __restrict__ out) {
    __shared__ float lb1[32], lw2[32];
    int tid = threadIdx.x;
    if (tid < 32) { lb1[tid] = b1[tid]; lw2[tid] = w2[tid]; }
    __syncthreads();
    int b = blockIdx.y;
    int n = blockIdx.x * 256 + tid;
    const float* pSns[3] = {ws + OFF_PSN0, ws + OFF_PSN1, ws + OFF_PSN2};
    const float* pSws[3] = {ws + OFF_PSW0, ws + OFF_PSW1, ws + OFF_PSW2};
    const int ncs[3] = {8, 8, 4};
    float aval[3];
#pragma unroll
    for (int s = 0; s < 3; ++s) {
        int nc = ncs[s];
        float Sn = 0.f, Sw = 0.f;
        for (int ch = 0; ch < nc; ++ch) {
            int pi = (b * nc + ch) * 4096 + n;
            Sn += pSns[s][pi];
            Sw += pSws[s][pi];
        }
        float bav = (s == 0) ? ba0[0] : (s == 1) ? ba1[0] : ba2[0];
        aval[s] = Sw / Sn + bav;
    }
    float prod = aval[0] * aval[1] * aval[2];
    int oy = n >> 6, ox = n & 63;
    float f0 = 15.0f / 63.0f;
    float cy0 = oy * f0, cx0 = ox * f0;
    int iy0 = min((int)cy0, 14), ix0 = min((int)cx0, 14);
    float wy0 = cy0 - iy0, wx0 = cx0 - ix0;
    float f1 = 31.0f / 63.0f;
    float cy1 = oy * f1, cx1 = ox * f1;
    int iy1 = min((int)cy1, 30), ix1 = min((int)cx1, 30);
    float wy1 = cy1 - iy1, wx1 = cx1 - ix1;
    const float* g0b = ws + OFF_PROJ0 + (b * 161 + 129) * 256;
    const float* g1b = ws + OFF_PROJ1 + (b * 97 + 65) * 1024;
    const float* g2b = ws + OFF_PROJ2 + (b * 65 + 33) * 4096;
    float outv = 0.f;
#pragma unroll 4
    for (int j = 0; j < 32; ++j) {
        const float* p0 = g0b + j * 256;
        float v0 = (1.f - wy0) * ((1.f - wx0) * p0[iy0 * 16 + ix0] + wx0 * p0[iy0 * 16 + ix0 + 1]) +
                   wy0 * ((1.f - wx0) * p0[(iy0 + 1) * 16 + ix0] + wx0 * p0[(iy0 + 1) * 16 + ix0 + 1]);
        const float* p1 = g1b + j * 1024;
        float v1 = (1.f - wy1) * ((1.f - wx1) * p1[iy1 * 32 + ix1] + wx1 * p1[iy1 * 32 + ix1 + 1]) +
                   wy1 * ((1.f - wx1) * p1[(iy1 + 1) * 32 + ix1] + wx1 * p1[(iy1 + 1) * 32 + ix1 + 1]);
        float g = g2b[j * 4096 + n] + v0 + v1;
        float h = fmaxf(prod * g + lb1[j], 0.f);
        outv += lw2[j] * h;
    }
    out[b * 4096 + n] = outv + b2[0];
}

// ---------------------------------------------------------------------------
extern "C" void kernel_launch(void* const* d_in, const int* in_sizes, int n_in,
                              void* d_out, int out_size, void* d_ws, size_t ws_size,
                              hipStream_t stream) {
    const float* x3 = (const float*)d_in[0];
    const float* x2 = (const float*)d_in[1];
    const float* x1 = (const float*)d_in[2];
    const float* W[24];
    for (int i = 0; i < 24; ++i) W[i] = (const float*)d_in[3 + i];
    const float* w1 = (const float*)d_in[27];
    const float* b1 = (const float*)d_in[28];
    const float* w2 = (const float*)d_in[29];
    const float* b2 = (const float*)d_in[30];
    float* ws = (float*)d_ws;
    float* out = (float*)d_out;

    UArgs ua;
    ua.wv0 = W[4];  ua.wa0 = W[6];  ua.bv0 = W[5];
    ua.wv1 = W[12]; ua.wa1 = W[14]; ua.bv1 = W[13];
    ua.wv2 = W[20]; ua.wa2 = W[22]; ua.bv2 = W[21];
    ua.ws = ws;
    u_kernel<<<56, 256, 0, stream>>>(ua);

    ProjArgs ja;
    ja.x0 = x1; ja.x1 = x2; ja.x2 = x3;
    ja.wq0 = W[0];  ja.wk0 = W[2];  ja.bq0 = W[1];  ja.bk0 = W[3];
    ja.wq1 = W[8];  ja.wk1 = W[10]; ja.bq1 = W[9];  ja.bk1 = W[11];
    ja.wq2 = W[16]; ja.wk2 = W[18]; ja.bq2 = W[17]; ja.bk2 = W[19];
    ja.w1 = w1; ja.ws = ws;
    proj_kernel<<<868, 256, 0, stream>>>(ja);

    aux_kernel<<<192, 256, 0, stream>>>(ws);

    // native logit tables
    lnat_kernel<64, 256, 1><<<dim3(32, BB), 256, 0, stream>>>(
        ws + OFF_PROJ0, 161, ws + OFF_LN0);
    lnat_kernel<32, 1024, 4><<<dim3(128, BB), 256, 0, stream>>>(
        ws + OFF_PROJ1, 97, ws + OFF_LN1);

    // fused bilerp attention: grid (oyc=8, noy=64, b)
    attnf_kernel<16, 4><<<dim3(8, 64, BB), 256, 0, stream>>>(
        ws + OFF_LN0, ws + OFF_SBIG0, ws + OFF_PSN0, ws + OFF_PSW0);
    attnf_kernel<32, 6><<<dim3(8, 64, BB), 256, 0, stream>>>(
        ws + OFF_LN1, ws + OFF_SBIG1, ws + OFF_PSN1, ws + OFF_PSW1);

    // scale2 MFMA flash attention: grid (64 n-blocks, 4 m-chunks, B)
    attn2_mfma_kernel<<<dim3(64, 4, BB), 256, 0, stream>>>(
        ws, (const ushort*)(ws + OFF_KP), ws + OFF_PSN2, ws + OFF_PSW2);

    final_kernel<<<dim3(16, BB), 256, 0, stream>>>(ws, W[7], W[15], W[23],
                                                   b1, w2, b2, out);
}